// Round 3
// baseline (1197.965 us; speedup 1.0000x reference)
//
#include <hip/hip_runtime.h>
#include <math.h>

#define B_ 64
#define N_ 512
#define P_ 512
#define E_ 128
#define F_ 512
#define L_ 6
#define SQRT_E_INV 0.08838834764831843f

typedef unsigned short u16;
typedef __attribute__((ext_vector_type(8))) short bf8;
typedef __attribute__((ext_vector_type(16))) float f16v;

__device__ inline u16 bf16r(float f) {
    unsigned u = __float_as_uint(f);
    u += 0x7fffu + ((u >> 16) & 1u);
    return (u16)(u >> 16);
}
__device__ inline float bf2f(u16 h) { return __uint_as_float((unsigned)h << 16); }

#define MFMA(a, b, c) __builtin_amdgcn_mfma_f32_32x32x16_bf16(a, b, c, 0, 0, 0)

// ===========================================================================
// qvk3_k: fused q/v/k for encoder layers. Tile 64 rows x 128 cols, K=128.
// 6 B planes (qh,ql,vh,vl,kh,kl). Epilogues: sigmoid(q)->sq16[n][e],
// ek=exp(k)->y2t[b][128+e][n], ekv=bf16(v)*ek->y2t[b][e][n].
// ===========================================================================
struct Q3 {
    const u16 *A0, *A1;
    const u16 *qh, *ql, *vh, *vl, *kh, *kl;
    u16 *sq16, *y2t;
};

__launch_bounds__(256, 2) __global__ void qvk3_k(Q3 p)
{
    const int tid = threadIdx.x;
    const int lane = tid & 63, wv = tid >> 6;
    const int wm = wv & 1, wn = wv >> 1;
    const int ln = lane & 31, hk = lane >> 5;
    const int row0 = blockIdx.x * 64;

    __shared__ __align__(16) u16 As[2][64][40];
    __shared__ __align__(16) u16 Bs[6][128][40];

    f16v aq[2], av[2], ak[2];
#pragma unroll
    for (int nt = 0; nt < 2; ++nt)
#pragma unroll
        for (int q = 0; q < 16; ++q) { aq[nt][q] = 0.f; av[nt][q] = 0.f; ak[nt][q] = 0.f; }

    const int r = tid >> 2, kq = tid & 3;
    for (int k0 = 0; k0 < 128; k0 += 32) {
        size_t ga = (size_t)(row0 + r) * 128 + k0 + kq * 8;
        *(uint4*)&As[0][r][kq * 8] = *(const uint4*)(p.A0 + ga);
        *(uint4*)&As[1][r][kq * 8] = *(const uint4*)(p.A1 + ga);
#pragma unroll
        for (int i = 0; i < 2; ++i) {
            int s = tid + i * 256;
            int rb2 = s >> 2, q = s & 3;
            size_t gb = (size_t)rb2 * 128 + k0 + q * 8;
            *(uint4*)&Bs[0][rb2][q * 8] = *(const uint4*)(p.qh + gb);
            *(uint4*)&Bs[1][rb2][q * 8] = *(const uint4*)(p.ql + gb);
            *(uint4*)&Bs[2][rb2][q * 8] = *(const uint4*)(p.vh + gb);
            *(uint4*)&Bs[3][rb2][q * 8] = *(const uint4*)(p.vl + gb);
            *(uint4*)&Bs[4][rb2][q * 8] = *(const uint4*)(p.kh + gb);
            *(uint4*)&Bs[5][rb2][q * 8] = *(const uint4*)(p.kl + gb);
        }
        __syncthreads();
#pragma unroll
        for (int s = 0; s < 2; ++s) {
            bf8 ah = *(const bf8*)&As[0][wm * 32 + ln][s * 16 + hk * 8];
            bf8 al = *(const bf8*)&As[1][wm * 32 + ln][s * 16 + hk * 8];
#pragma unroll
            for (int nt = 0; nt < 2; ++nt) {
                const int br = wn * 64 + nt * 32 + ln, sc = s * 16 + hk * 8;
                bf8 bqh = *(const bf8*)&Bs[0][br][sc];
                bf8 bql = *(const bf8*)&Bs[1][br][sc];
                bf8 bvh = *(const bf8*)&Bs[2][br][sc];
                bf8 bvl = *(const bf8*)&Bs[3][br][sc];
                bf8 bkh = *(const bf8*)&Bs[4][br][sc];
                bf8 bkl = *(const bf8*)&Bs[5][br][sc];
                aq[nt] = MFMA(ah, bqh, aq[nt]);
                aq[nt] = MFMA(ah, bql, aq[nt]);
                aq[nt] = MFMA(al, bqh, aq[nt]);
                av[nt] = MFMA(ah, bvh, av[nt]);
                av[nt] = MFMA(ah, bvl, av[nt]);
                av[nt] = MFMA(al, bvh, av[nt]);
                ak[nt] = MFMA(ah, bkh, ak[nt]);
                ak[nt] = MFMA(ah, bkl, ak[nt]);
                ak[nt] = MFMA(al, bkh, ak[nt]);
            }
        }
        __syncthreads();
    }

#pragma unroll
    for (int nt = 0; nt < 2; ++nt) {
        int gn = wn * 64 + nt * 32 + ln;
#pragma unroll
        for (int g = 0; g < 4; ++g) {
            int rb = row0 + wm * 32 + g * 8 + hk * 4;
            int bb = rb >> 9, nb = rb & 511;
            u16 pe[4], pv[4];
#pragma unroll
            for (int rr = 0; rr < 4; ++rr) {
                float vq = aq[nt][g * 4 + rr];
                p.sq16[(size_t)(rb + rr) * 128 + gn] =
                    bf16r(1.f / (1.f + __expf(-vq)));
                u16 hv = bf16r(av[nt][g * 4 + rr]);
                u16 he = bf16r(__expf(ak[nt][g * 4 + rr]));
                pe[rr] = he;
                pv[rr] = bf16r(bf2f(hv) * bf2f(he));
            }
            uint2 ue, uv;
            ue.x = pe[0] | ((unsigned)pe[1] << 16);
            ue.y = pe[2] | ((unsigned)pe[3] << 16);
            uv.x = pv[0] | ((unsigned)pv[1] << 16);
            uv.y = pv[2] | ((unsigned)pv[3] << 16);
            *(uint2*)(p.y2t + (size_t)bb * 131072 + (size_t)gn * 512 + nb) = uv;
            *(uint2*)(p.y2t + (size_t)bb * 131072 + (size_t)(128 + gn) * 512 + nb) = ue;
        }
    }
}

// ===========================================================================
// qvk_vk_k: decoder v/k (no q). Same as qvk3 minus the q planes.
// ===========================================================================
struct QV {
    const u16 *A0, *A1;
    const u16 *vh, *vl, *kh, *kl;
    u16* y2t;
};

__launch_bounds__(256, 3) __global__ void qvk_vk_k(QV p)
{
    const int tid = threadIdx.x;
    const int lane = tid & 63, wv = tid >> 6;
    const int wm = wv & 1, wn = wv >> 1;
    const int ln = lane & 31, hk = lane >> 5;
    const int row0 = blockIdx.x * 64;

    __shared__ __align__(16) u16 As[2][64][40];
    __shared__ __align__(16) u16 Bs[4][128][40];

    f16v av[2], ak[2];
#pragma unroll
    for (int nt = 0; nt < 2; ++nt)
#pragma unroll
        for (int q = 0; q < 16; ++q) { av[nt][q] = 0.f; ak[nt][q] = 0.f; }

    const int r = tid >> 2, kq = tid & 3;
    for (int k0 = 0; k0 < 128; k0 += 32) {
        size_t ga = (size_t)(row0 + r) * 128 + k0 + kq * 8;
        *(uint4*)&As[0][r][kq * 8] = *(const uint4*)(p.A0 + ga);
        *(uint4*)&As[1][r][kq * 8] = *(const uint4*)(p.A1 + ga);
#pragma unroll
        for (int i = 0; i < 2; ++i) {
            int s = tid + i * 256;
            int rb2 = s >> 2, q = s & 3;
            size_t gb = (size_t)rb2 * 128 + k0 + q * 8;
            *(uint4*)&Bs[0][rb2][q * 8] = *(const uint4*)(p.vh + gb);
            *(uint4*)&Bs[1][rb2][q * 8] = *(const uint4*)(p.vl + gb);
            *(uint4*)&Bs[2][rb2][q * 8] = *(const uint4*)(p.kh + gb);
            *(uint4*)&Bs[3][rb2][q * 8] = *(const uint4*)(p.kl + gb);
        }
        __syncthreads();
#pragma unroll
        for (int s = 0; s < 2; ++s) {
            bf8 ah = *(const bf8*)&As[0][wm * 32 + ln][s * 16 + hk * 8];
            bf8 al = *(const bf8*)&As[1][wm * 32 + ln][s * 16 + hk * 8];
#pragma unroll
            for (int nt = 0; nt < 2; ++nt) {
                const int br = wn * 64 + nt * 32 + ln, sc = s * 16 + hk * 8;
                bf8 bvh = *(const bf8*)&Bs[0][br][sc];
                bf8 bvl = *(const bf8*)&Bs[1][br][sc];
                bf8 bkh = *(const bf8*)&Bs[2][br][sc];
                bf8 bkl = *(const bf8*)&Bs[3][br][sc];
                av[nt] = MFMA(ah, bvh, av[nt]);
                av[nt] = MFMA(ah, bvl, av[nt]);
                av[nt] = MFMA(al, bvh, av[nt]);
                ak[nt] = MFMA(ah, bkh, ak[nt]);
                ak[nt] = MFMA(ah, bkl, ak[nt]);
                ak[nt] = MFMA(al, bkh, ak[nt]);
            }
        }
        __syncthreads();
    }

#pragma unroll
    for (int nt = 0; nt < 2; ++nt) {
        int gn = wn * 64 + nt * 32 + ln;
#pragma unroll
        for (int g = 0; g < 4; ++g) {
            int rb = row0 + wm * 32 + g * 8 + hk * 4;
            int bb = rb >> 9, nb = rb & 511;
            u16 pe[4], pv[4];
#pragma unroll
            for (int rr = 0; rr < 4; ++rr) {
                u16 hv = bf16r(av[nt][g * 4 + rr]);
                u16 he = bf16r(__expf(ak[nt][g * 4 + rr]));
                pe[rr] = he;
                pv[rr] = bf16r(bf2f(hv) * bf2f(he));
            }
            uint2 ue, uv;
            ue.x = pe[0] | ((unsigned)pe[1] << 16);
            ue.y = pe[2] | ((unsigned)pe[3] << 16);
            uv.x = pv[0] | ((unsigned)pv[1] << 16);
            uv.y = pv[2] | ((unsigned)pv[3] << 16);
            *(uint2*)(p.y2t + (size_t)bb * 131072 + (size_t)gn * 512 + nb) = uv;
            *(uint2*)(p.y2t + (size_t)bb * 131072 + (size_t)(128 + gn) * 512 + nb) = ue;
        }
    }
}

// ===========================================================================
// aft2_k: AFT aggregation with num AND den in one block.
// C_num = exp(as*A(+M)) @ ekv^T, C_den = same @ ek^T; out = [sg*]num/den
// written as bf16 hi/lo planes [b][n][e]. Tile 64 rows x 128 e (num+den =
// 256 B-rows), K=512 step 32, reg-staged LDS double buffer.
// Grid 512, XCD-grouped: all 8 row-blocks of a bz on one XCD (B L2-shared).
// ===========================================================================
struct AP2 {
    const float *A0, *A1;    // dist / cur_dist, mask (OPA==2)
    const u16 *B0, *sq;      // y2t, sigmoid plane (SG==1)
    u16 *gh, *gl;
    const float *s1, *s2; int s2i;
};

template <int OPA, int SG>   // OPA1: exp(as*A); OPA2: exp(as*A + M)
__launch_bounds__(256, 3) __global__ void aft2_k(AP2 p)
{
    const int tid = threadIdx.x;
    const int lane = tid & 63, wv = tid >> 6;
    const int wm = wv & 1, wn = wv >> 1;
    const int ln = lane & 31, hk = lane >> 5;

    const int id = blockIdx.x;
    const int xcd = id & 7, slot = id >> 3;
    const int bz = xcd * 8 + (slot >> 3);
    const int row0 = (slot & 7) * 64;

    __shared__ __align__(16) u16 As[2][64][40];
    __shared__ __align__(16) u16 Bs[2][256][40];

    f16v acc[4];
#pragma unroll
    for (int j = 0; j < 4; ++j)
#pragma unroll
        for (int q = 0; q < 16; ++q) acc[j][q] = 0.f;

    const float ascale = p.s1[0] * p.s2[p.s2i];
    const float* Af = p.A0 + (size_t)bz * 262144 + (size_t)row0 * 512;
    const float* Mf = (OPA == 2)
        ? (p.A1 + (size_t)bz * 262144 + (size_t)row0 * 512) : (const float*)0;
    const u16* Bb = p.B0 + (size_t)bz * 131072;

    const int r = tid >> 2, kq = tid & 3;    // A: 64 rows x 32 fp32
    float fa[8], fm[8];
    uint4 vb[4];

#define AFT_LOAD(K0)                                                          \
    {                                                                         \
        size_t ga = (size_t)r * 512 + (K0) + kq * 8;                          \
        *(float4*)&fa[0] = *(const float4*)(Af + ga);                         \
        *(float4*)&fa[4] = *(const float4*)(Af + ga + 4);                     \
        if (OPA == 2) {                                                       \
            *(float4*)&fm[0] = *(const float4*)(Mf + ga);                     \
            *(float4*)&fm[4] = *(const float4*)(Mf + ga + 4);                 \
        }                                                                     \
        size_t gb = (size_t)tid * 512 + (K0);                                 \
        _Pragma("unroll") for (int q = 0; q < 4; ++q)                         \
            vb[q] = *(const uint4*)(Bb + gb + q * 8);                         \
    }

#define AFT_WRITE(BUF)                                                        \
    {                                                                         \
        float f[8];                                                           \
        _Pragma("unroll") for (int j = 0; j < 8; ++j) {                       \
            float t = (OPA == 2) ? fmaf(ascale, fa[j], fm[j]) : ascale * fa[j]; \
            f[j] = __expf(t);                                                 \
        }                                                                     \
        uint4 pk;                                                             \
        pk.x = bf16r(f[0]) | ((unsigned)bf16r(f[1]) << 16);                   \
        pk.y = bf16r(f[2]) | ((unsigned)bf16r(f[3]) << 16);                   \
        pk.z = bf16r(f[4]) | ((unsigned)bf16r(f[5]) << 16);                   \
        pk.w = bf16r(f[6]) | ((unsigned)bf16r(f[7]) << 16);                   \
        *(uint4*)&As[BUF][r][kq * 8] = pk;                                    \
        _Pragma("unroll") for (int q = 0; q < 4; ++q)                         \
            *(uint4*)&Bs[BUF][tid][q * 8] = vb[q];                            \
    }

#define AFT_COMPUTE(BUF)                                                      \
    {                                                                         \
        _Pragma("unroll") for (int s = 0; s < 2; ++s) {                       \
            bf8 ah = *(const bf8*)&As[BUF][wm * 32 + ln][s * 16 + hk * 8];    \
            _Pragma("unroll") for (int j = 0; j < 4; ++j) {                   \
                int br = ((j >> 1) << 7) + wn * 64 + ((j & 1) << 5) + ln;     \
                bf8 bh = *(const bf8*)&Bs[BUF][br][s * 16 + hk * 8];          \
                acc[j] = MFMA(ah, bh, acc[j]);                                \
            }                                                                 \
        }                                                                     \
    }

    AFT_LOAD(0);
    AFT_WRITE(0);
    __syncthreads();

    int cur = 0;
    for (int k0 = 32; k0 < 512; k0 += 32) {
        AFT_LOAD(k0);
        AFT_COMPUTE(cur);
        AFT_WRITE(cur ^ 1);
        __syncthreads();
        cur ^= 1;
    }
    AFT_COMPUTE(cur);

#undef AFT_LOAD
#undef AFT_WRITE
#undef AFT_COMPUTE

    const u16* sqb = SG ? (p.sq + (size_t)bz * 65536) : (const u16*)0;
    u16* ghb = p.gh + (size_t)bz * 65536;
    u16* glb = p.gl + (size_t)bz * 65536;
#pragma unroll
    for (int j = 0; j < 2; ++j) {
        int e = wn * 64 + j * 32 + ln;
#pragma unroll
        for (int g = 0; g < 4; ++g) {
#pragma unroll
            for (int rr = 0; rr < 4; ++rr) {
                int row = row0 + wm * 32 + g * 8 + hk * 4 + rr;
                float num = acc[j][g * 4 + rr];
                float den = acc[j + 2][g * 4 + rr];
                float pv = num / den;
                if (SG) pv *= bf2f(sqb[(size_t)row * 128 + e]);
                u16 hi = bf16r(pv);
                ghb[(size_t)row * 128 + e] = hi;
                glb[(size_t)row * 128 + e] = bf16r(pv - bf2f(hi));
            }
        }
    }
}

// ===========================================================================
// ffn12_k: fused FFN. Block = 64 rows, 512 threads (8 waves, 2x4).
// Phase 1: ff1 = relu(h@W1+b1) -> LDS (bf16, 4 chunks of 128 cols).
// Phase 2: ff2 = ff1@W2+b2 -> fp32 global. ff1 never touches HBM.
// A fragments (h hi/lo) live in registers, reused across chunks.
// ===========================================================================
struct F12 {
    const u16 *A0, *A1;        // h hi/lo [B*N][128]
    const u16 *w1h, *w1l;      // [512][128] (n-major, k inner)
    const u16 *w2h, *w2l;      // [128][512]
    const float *b1, *b2;      // [512], [128]
    float* of;                 // ff2 [B*N][128]
};

__launch_bounds__(512, 2) __global__ void ffn12_k(F12 p)
{
    const int tid = threadIdx.x;
    const int lane = tid & 63, wv = tid >> 6;
    const int wm = wv & 1, wn = wv >> 1;          // wn in 0..3
    const int ln = lane & 31, hk = lane >> 5;
    const int row0 = blockIdx.x * 64;

    __shared__ __align__(16) u16 Bs[2][128][136];    // 68 KB staging
    __shared__ __align__(16) u16 ff1c[4][64][136];   // 68 KB ff1 tile

    // A fragments: 8 K-slices x hi/lo, loaded once, reused for all chunks
    bf8 ar0[8], ar1[8];
    {
        const size_t arow = (size_t)(row0 + wm * 32 + ln) * 128;
#pragma unroll
        for (int s = 0; s < 8; ++s) {
            ar0[s] = *(const bf8*)(p.A0 + arow + s * 16 + hk * 8);
            ar1[s] = *(const bf8*)(p.A1 + arow + s * 16 + hk * 8);
        }
    }

    const int lcol = wn * 32 + ln;

    // ---- phase 1 ----
    for (int ct = 0; ct < 4; ++ct) {
#pragma unroll
        for (int i = 0; i < 4; ++i) {
            int idx = tid + i * 512;               // 0..2047
            int col = idx >> 4, q = idx & 15;
            size_t gb = (size_t)(ct * 128 + col) * 128 + q * 8;
            *(uint4*)&Bs[0][col][q * 8] = *(const uint4*)(p.w1h + gb);
            *(uint4*)&Bs[1][col][q * 8] = *(const uint4*)(p.w1l + gb);
        }
        __syncthreads();

        f16v a0, a1, a2;
#pragma unroll
        for (int q = 0; q < 16; ++q) { a0[q] = 0.f; a1[q] = 0.f; a2[q] = 0.f; }
#pragma unroll
        for (int s = 0; s < 8; ++s) {
            bf8 bh = *(const bf8*)&Bs[0][lcol][s * 16 + hk * 8];
            bf8 bl = *(const bf8*)&Bs[1][lcol][s * 16 + hk * 8];
            a0 = MFMA(ar0[s], bh, a0);
            a1 = MFMA(ar0[s], bl, a1);
            a2 = MFMA(ar1[s], bh, a2);
        }
        __syncthreads();

        float bv = p.b1[ct * 128 + lcol];
#pragma unroll
        for (int g = 0; g < 4; ++g) {
#pragma unroll
            for (int rr = 0; rr < 4; ++rr) {
                int lr = wm * 32 + g * 8 + hk * 4 + rr;
                float v = a0[g * 4 + rr] + a1[g * 4 + rr] + a2[g * 4 + rr] + bv;
                ff1c[ct][lr][lcol] = bf16r(fmaxf(v, 0.f));
            }
        }
    }
    __syncthreads();

    // ---- phase 2 ----
    f16v c0, c1;
#pragma unroll
    for (int q = 0; q < 16; ++q) { c0[q] = 0.f; c1[q] = 0.f; }
    for (int kc = 0; kc < 4; ++kc) {
#pragma unroll
        for (int i = 0; i < 4; ++i) {
            int idx = tid + i * 512;
            int col = idx >> 4, q = idx & 15;
            size_t gb = (size_t)col * 512 + kc * 128 + q * 8;
            *(uint4*)&Bs[0][col][q * 8] = *(const uint4*)(p.w2h + gb);
            *(uint4*)&Bs[1][col][q * 8] = *(const uint4*)(p.w2l + gb);
        }
        __syncthreads();
#pragma unroll
        for (int s = 0; s < 8; ++s) {
            bf8 af = *(const bf8*)&ff1c[kc][wm * 32 + ln][s * 16 + hk * 8];
            bf8 bh = *(const bf8*)&Bs[0][lcol][s * 16 + hk * 8];
            bf8 bl = *(const bf8*)&Bs[1][lcol][s * 16 + hk * 8];
            c0 = MFMA(af, bh, c0);
            c1 = MFMA(af, bl, c1);
        }
        __syncthreads();
    }

    float bv = p.b2[lcol];
#pragma unroll
    for (int g = 0; g < 4; ++g) {
#pragma unroll
        for (int rr = 0; rr < 4; ++rr) {
            int rb = row0 + wm * 32 + g * 8 + hk * 4 + rr;
            p.of[(size_t)rb * 128 + lcol] = c0[g * 4 + rr] + c1[g * 4 + rr] + bv;
        }
    }
}

// ===========================================================================
// score_sm_k: fused score + softmax. Block owns 64 p-rows x full 512 n of one
// batch. score = 10*tanh(aft@enc^T/sqrtE + sp*cd) + cm; probs = softmax(row).
// No max-subtraction needed: score bounded by +-10 (+mask), exp is safe.
// exp values held in registers (accs[4][2]); row sums reduced via shfl + LDS.
// Grid 512, XCD-grouped per batch.
// ===========================================================================
struct SP2 {
    const u16 *A0, *A1, *B0, *B1;
    float* out;
    const float *cd, *cm;
    const float *s1, *s2;
};

__launch_bounds__(256, 2) __global__ void score_sm_k(SP2 p)
{
    const int tid = threadIdx.x;
    const int lane = tid & 63, wv = tid >> 6;
    const int wm = wv & 1, wn = wv >> 1;
    const int ln = lane & 31, hk = lane >> 5;

    const int id = blockIdx.x;
    const int xcd = id & 7, s_ = id >> 3;          // s_ in 0..63
    const int bz = xcd * 8 + (s_ & 7);
    const int row0 = (s_ >> 3) * 64;

    __shared__ __align__(16) u16 As[2][64][136];   // aft hi/lo, full K=128
    __shared__ __align__(16) u16 Bs[2][128][72];   // enc chunk, K=64
    __shared__ float rs[2][64];

    // stage A once
#pragma unroll
    for (int i = 0; i < 8; ++i) {
        int idx = tid + i * 256;                   // 0..2047
        int pl = idx >> 10, rem = idx & 1023;
        int row = rem >> 4, q = rem & 15;
        const u16* src = pl ? p.A1 : p.A0;
        *(uint4*)&As[pl][row][q * 8] =
            *(const uint4*)(src + ((size_t)bz * 512 + row0 + row) * 128 + q * 8);
    }

    const float sp = p.s1[0] * p.s2[0];
    f16v accs[4][2];
    float rsum[16];
#pragma unroll
    for (int i = 0; i < 16; ++i) rsum[i] = 0.f;

#pragma unroll
    for (int ct = 0; ct < 4; ++ct) {
#pragma unroll
        for (int nt = 0; nt < 2; ++nt)
#pragma unroll
            for (int q = 0; q < 16; ++q) accs[ct][nt][q] = 0.f;

        for (int kc = 0; kc < 128; kc += 64) {
#pragma unroll
            for (int i = 0; i < 8; ++i) {
                int idx = tid + i * 256;
                int pl = idx >> 10, rem = idx & 1023;
                int row = rem >> 3, q = rem & 7;
                const u16* src = pl ? p.B1 : p.B0;
                *(uint4*)&Bs[pl][row][q * 8] =
                    *(const uint4*)(src + ((size_t)bz * 512 + ct * 128 + row) * 128
                                    + kc + q * 8);
            }
            __syncthreads();
#pragma unroll
            for (int s = 0; s < 4; ++s) {
                bf8 ah = *(const bf8*)&As[0][wm * 32 + ln][kc + s * 16 + hk * 8];
                bf8 al = *(const bf8*)&As[1][wm * 32 + ln][kc + s * 16 + hk * 8];
#pragma unroll
                for (int nt = 0; nt < 2; ++nt) {
                    bf8 bh = *(const bf8*)&Bs[0][wn * 64 + nt * 32 + ln][s * 16 + hk * 8];
                    bf8 bl = *(const bf8*)&Bs[1][wn * 64 + nt * 32 + ln][s * 16 + hk * 8];
                    accs[ct][nt] = MFMA(ah, bh, accs[ct][nt]);
                    accs[ct][nt] = MFMA(ah, bl, accs[ct][nt]);
                    accs[ct][nt] = MFMA(al, bh, accs[ct][nt]);
                }
            }
            __syncthreads();
        }

        // epilogue ct: score -> exp (kept in accs), accumulate row sums
#pragma unroll
        for (int nt = 0; nt < 2; ++nt) {
            int gn = ct * 128 + wn * 64 + nt * 32 + ln;
#pragma unroll
            for (int g = 0; g < 4; ++g) {
#pragma unroll
                for (int rr = 0; rr < 4; ++rr) {
                    int grow = row0 + wm * 32 + g * 8 + hk * 4 + rr;
                    size_t ix = (size_t)bz * 262144 + (size_t)grow * 512 + gn;
                    float sc = fmaf(accs[ct][nt][g * 4 + rr], SQRT_E_INV,
                                    sp * p.cd[ix]);
                    float e2 = __expf(2.f * sc);
                    float th = 1.f - 2.f / (e2 + 1.f);
                    float ev = __expf(10.f * th + p.cm[ix]);
                    accs[ct][nt][g * 4 + rr] = ev;
                    rsum[g * 4 + rr] += ev;
                }
            }
        }
    }

    // reduce row sums over the 32 ln-lanes (bit 5 = hk untouched)
#pragma unroll
    for (int i = 0; i < 16; ++i) {
#pragma unroll
        for (int o = 1; o < 32; o <<= 1) rsum[i] += __shfl_xor(rsum[i], o);
    }
    __syncthreads();
    if (ln == 0) {
#pragma unroll
        for (int i = 0; i < 16; ++i) {
            int lr = wm * 32 + (i >> 2) * 8 + hk * 4 + (i & 3);
            rs[wn][lr] = rsum[i];
        }
    }
    __syncthreads();
    float invr[16];
#pragma unroll
    for (int i = 0; i < 16; ++i) {
        int lr = wm * 32 + (i >> 2) * 8 + hk * 4 + (i & 3);
        invr[i] = 1.f / (rs[0][lr] + rs[1][lr]);
    }

    // write normalized probabilities
#pragma unroll
    for (int ct = 0; ct < 4; ++ct)
#pragma unroll
        for (int nt = 0; nt < 2; ++nt) {
            int gn = ct * 128 + wn * 64 + nt * 32 + ln;
#pragma unroll
            for (int g = 0; g < 4; ++g)
#pragma unroll
                for (int rr = 0; rr < 4; ++rr) {
                    int grow = row0 + wm * 32 + g * 8 + hk * 4 + rr;
                    size_t ix = (size_t)bz * 262144 + (size_t)grow * 512 + gn;
                    p.out[ix] = accs[ct][nt][g * 4 + rr] * invr[g * 4 + rr];
                }
        }
}

// ===========================================================================
// InstanceNorm over nodes, residual fused.
// MODE1: val = (ah+al) + (g0+g1)  [two bf16 planes];  MODE2: val = (ah+al) + f1
// ===========================================================================
template <int MODE>
__launch_bounds__(256) __global__ void inorm_k(
    const u16* __restrict__ ah, const u16* __restrict__ al,
    const u16* __restrict__ g0, const u16* __restrict__ g1,
    const float* __restrict__ f1,
    const float* __restrict__ nw, const float* __restrict__ nbv,
    u16* __restrict__ oh, u16* __restrict__ ol)
{
    const int bb = blockIdx.x, e0 = blockIdx.y * 16;
    const int tid = threadIdx.x, el = tid & 3, no = tid >> 2;
    const size_t base = (size_t)bb * N_ * E_ + e0 + el * 4;

    float4 vals[8];
    float s1x = 0, s1y = 0, s1z = 0, s1w = 0;
    float s2x = 0, s2y = 0, s2z = 0, s2w = 0;
#pragma unroll
    for (int i = 0; i < 8; ++i) {
        int n = no * 8 + i;
        size_t ad = base + (size_t)n * E_;
        uint2 h2 = *(const uint2*)(ah + ad);
        uint2 l2 = *(const uint2*)(al + ad);
        float x0 = bf2f((u16)h2.x) + bf2f((u16)l2.x);
        float x1 = bf2f((u16)(h2.x >> 16)) + bf2f((u16)(l2.x >> 16));
        float x2 = bf2f((u16)h2.y) + bf2f((u16)l2.y);
        float x3 = bf2f((u16)(h2.y >> 16)) + bf2f((u16)(l2.y >> 16));
        float4 v;
        if (MODE == 1) {
            uint2 a2 = *(const uint2*)(g0 + ad);
            uint2 b2 = *(const uint2*)(g1 + ad);
            v.x = x0 + bf2f((u16)a2.x) + bf2f((u16)b2.x);
            v.y = x1 + bf2f((u16)(a2.x >> 16)) + bf2f((u16)(b2.x >> 16));
            v.z = x2 + bf2f((u16)a2.y) + bf2f((u16)b2.y);
            v.w = x3 + bf2f((u16)(a2.y >> 16)) + bf2f((u16)(b2.y >> 16));
        } else {
            float4 ff = *(const float4*)(f1 + ad);
            v.x = x0 + ff.x; v.y = x1 + ff.y; v.z = x2 + ff.z; v.w = x3 + ff.w;
        }
        vals[i] = v;
        s1x += v.x; s1y += v.y; s1z += v.z; s1w += v.w;
        s2x = fmaf(v.x, v.x, s2x); s2y = fmaf(v.y, v.y, s2y);
        s2z = fmaf(v.z, v.z, s2z); s2w = fmaf(v.w, v.w, s2w);
    }

    __shared__ float4 r1[256], r2[256];
    r1[tid] = make_float4(s1x, s1y, s1z, s1w);
    r2[tid] = make_float4(s2x, s2y, s2z, s2w);
    __syncthreads();
    for (int s = 128; s >= 4; s >>= 1) {
        if (tid < s) {
            float4 u = r1[tid], w = r1[tid + s];
            r1[tid] = make_float4(u.x + w.x, u.y + w.y, u.z + w.z, u.w + w.w);
            float4 pq = r2[tid], q = r2[tid + s];
            r2[tid] = make_float4(pq.x + q.x, pq.y + q.y, pq.z + q.z, pq.w + q.w);
        }
        __syncthreads();
    }
    __shared__ float4 mu_s[4], rs_s[4];
    if (tid < 4) {
        float4 m = r1[tid], q = r2[tid];
        m.x *= (1.f / N_); m.y *= (1.f / N_); m.z *= (1.f / N_); m.w *= (1.f / N_);
        q.x *= (1.f / N_); q.y *= (1.f / N_); q.z *= (1.f / N_); q.w *= (1.f / N_);
        float4 rsq;
        rsq.x = rsqrtf(q.x - m.x * m.x + 1e-5f);
        rsq.y = rsqrtf(q.y - m.y * m.y + 1e-5f);
        rsq.z = rsqrtf(q.z - m.z * m.z + 1e-5f);
        rsq.w = rsqrtf(q.w - m.w * m.w + 1e-5f);
        mu_s[tid] = m; rs_s[tid] = rsq;
    }
    __syncthreads();
    float4 mu = mu_s[el], rsq = rs_s[el];
    float4 w4 = *(const float4*)(nw + e0 + el * 4);
    float4 b4 = *(const float4*)(nbv + e0 + el * 4);
#pragma unroll
    for (int i = 0; i < 8; ++i) {
        size_t ad = base + (size_t)(no * 8 + i) * E_;
        float4 v = vals[i];
        v.x = fmaf((v.x - mu.x) * rsq.x, w4.x, b4.x);
        v.y = fmaf((v.y - mu.y) * rsq.y, w4.y, b4.y);
        v.z = fmaf((v.z - mu.z) * rsq.z, w4.z, b4.z);
        v.w = fmaf((v.w - mu.w) * rsq.w, w4.w, b4.w);
        u16 h0 = bf16r(v.x), h1 = bf16r(v.y), h2v = bf16r(v.z), h3 = bf16r(v.w);
        u16 l0 = bf16r(v.x - bf2f(h0)), l1 = bf16r(v.y - bf2f(h1));
        u16 l2v = bf16r(v.z - bf2f(h2v)), l3 = bf16r(v.w - bf2f(h3));
        uint2 ph, pl;
        ph.x = h0 | ((unsigned)h1 << 16); ph.y = h2v | ((unsigned)h3 << 16);
        pl.x = l0 | ((unsigned)l1 << 16); pl.y = l2v | ((unsigned)l3 << 16);
        *(uint2*)(oh + ad) = ph;
        *(uint2*)(ol + ad) = pl;
    }
}

// ===========================================================================
__global__ void wprep_k(const float* __restrict__ W, u16* __restrict__ Th,
                        u16* __restrict__ Tl, int K, int N)
{
    const int z = blockIdx.z;
    const float* Wz = W + (size_t)z * K * N;
    u16* Hh = Th + (size_t)z * K * N;
    u16* Hl = Tl + (size_t)z * K * N;
    __shared__ float t[32][33];
    const int j = threadIdx.x & 31, i0 = threadIdx.x >> 5;
    const int k0 = blockIdx.x * 32, n0 = blockIdx.y * 32;
    for (int i = i0; i < 32; i += 8)
        t[i][j] = Wz[(size_t)(k0 + i) * N + n0 + j];
    __syncthreads();
    for (int i = i0; i < 32; i += 8) {
        float v = t[j][i];
        u16 h = bf16r(v);
        u16 l = bf16r(v - bf2f(h));
        size_t o = (size_t)(n0 + i) * K + k0 + j;
        Hh[o] = h; Hl[o] = l;
    }
}

__global__ void embed_k(const float* __restrict__ data, const float* __restrict__ W,
                        const float* __restrict__ bias,
                        u16* __restrict__ xh, u16* __restrict__ xl)
{
    size_t idx = (size_t)blockIdx.x * 256 + threadIdx.x;
    int e = idx & 127;
    size_t bn = idx >> 7;
    float v = fmaf(data[bn * 2], W[e], fmaf(data[bn * 2 + 1], W[128 + e], bias[e]));
    u16 h = bf16r(v);
    xh[idx] = h;
    xl[idx] = bf16r(v - bf2f(h));
}

__launch_bounds__(512) __global__
void gq_k(const u16* __restrict__ xh, const u16* __restrict__ xl,
          const float* __restrict__ dWq, float* __restrict__ gq)
{
    int b = blockIdx.x;
    int tid = threadIdx.x;
    int e = tid & 127, qd = tid >> 7;
    float s = 0.f;
    for (int n = qd; n < N_; n += 4) {
        size_t ix = ((size_t)b * N_ + n) * E_ + e;
        s += bf2f(xh[ix]) + bf2f(xl[ix]);
    }
    __shared__ float part[512];
    __shared__ float gm[128];
    part[tid] = s;
    __syncthreads();
    if (tid < 128)
        gm[tid] = (part[tid] + part[tid + 128] + part[tid + 256] + part[tid + 384]) *
                  (1.f / N_);
    __syncthreads();
    if (tid < 128) {
        float acc = 0.f;
        for (int kk = 0; kk < 128; ++kk) acc = fmaf(gm[kk], dWq[kk * 128 + tid], acc);
        gq[b * 128 + tid] = acc;
    }
}

__global__ void dec_aft_k(const float* __restrict__ gq, const float* __restrict__ cap,
                          const float* __restrict__ dWq,
                          const u16* __restrict__ rh, const u16* __restrict__ rl,
                          u16* __restrict__ oh, u16* __restrict__ ol)
{
    size_t idx = (size_t)blockIdx.x * 256 + threadIdx.x;
    int e = idx & 127;
    size_t bp = idx >> 7;
    int b = (int)(bp >> 9);
    float q = fmaf(cap[bp], dWq[128 * 128 + e], gq[b * 128 + e]);
    float sg = 1.f / (1.f + __expf(-q));
    float v = sg * (bf2f(rh[idx]) + bf2f(rl[idx]));
    u16 h = bf16r(v);
    oh[idx] = h;
    ol[idx] = bf16r(v - bf2f(h));
}

// ===========================================================================
extern "C" void kernel_launch(void* const* d_in, const int* in_sizes, int n_in,
                              void* d_out, int out_size, void* d_ws, size_t ws_size,
                              hipStream_t stream)
{
    const float* data      = (const float*)d_in[0];
    const float* dist      = (const float*)d_in[1];
    const float* cur_dist  = (const float*)d_in[2];
    const float* capacity  = (const float*)d_in[3];
    const float* ninf      = (const float*)d_in[4];
    const float* log_scale = (const float*)d_in[5];
    const float* emb_W     = (const float*)d_in[6];
    const float* emb_b     = (const float*)d_in[7];
    const float* Wq        = (const float*)d_in[8];
    const float* Wk        = (const float*)d_in[9];
    const float* Wv        = (const float*)d_in[10];
    const float* aft_alpha = (const float*)d_in[11];
    const float* n1_w      = (const float*)d_in[12];
    const float* n1_b      = (const float*)d_in[13];
    const float* ffW1      = (const float*)d_in[14];
    const float* ffb1      = (const float*)d_in[15];
    const float* ffW2      = (const float*)d_in[16];
    const float* ffb2      = (const float*)d_in[17];
    const float* n2_w      = (const float*)d_in[18];
    const float* n2_b      = (const float*)d_in[19];
    const float* dWq       = (const float*)d_in[20];
    const float* dWk       = (const float*)d_in[21];
    const float* dWv       = (const float*)d_in[22];
    const float* dec_alpha = (const float*)d_in[23];
    const float* p_alpha   = (const float*)d_in[24];
    float* out = (float*)d_out;

    char* W = (char*)d_ws;
    size_t off = 0;
    auto take = [&](size_t n) { void* pp = W + off; off += (n + 255) & ~(size_t)255; return pp; };
    const size_t SZP = (size_t)B_ * N_ * E_ * 2;   // 8 MB bf16 plane

    u16* xh   = (u16*)take(SZP);
    u16* xl   = (u16*)take(SZP);
    u16* hh   = (u16*)take(SZP);
    u16* hl   = (u16*)take(SZP);
    u16* sq16 = (u16*)take(SZP);
    u16* gh   = (u16*)take(SZP);
    u16* gl   = (u16*)take(SZP);
    u16* y2t  = (u16*)take(2 * SZP);
    float* ff2 = (float*)take((size_t)B_ * N_ * E_ * 4);   // 16 MB fp32
    u16* wqt_h = (u16*)take(196608); u16* wqt_l = (u16*)take(196608);
    u16* wkt_h = (u16*)take(196608); u16* wkt_l = (u16*)take(196608);
    u16* wvt_h = (u16*)take(196608); u16* wvt_l = (u16*)take(196608);
    u16* w1t_h = (u16*)take(786432); u16* w1t_l = (u16*)take(786432);
    u16* w2t_h = (u16*)take(786432); u16* w2t_l = (u16*)take(786432);
    u16* dkt_h = (u16*)take(32768);  u16* dkt_l = (u16*)take(32768);
    u16* dvt_h = (u16*)take(32768);  u16* dvt_l = (u16*)take(32768);
    float* gq = (float*)take(32768);
    if (ws_size < off) return;

    // ---- weight prep ----
    wprep_k<<<dim3(4, 4, 6), 256, 0, stream>>>(Wq, wqt_h, wqt_l, 128, 128);
    wprep_k<<<dim3(4, 4, 6), 256, 0, stream>>>(Wk, wkt_h, wkt_l, 128, 128);
    wprep_k<<<dim3(4, 4, 6), 256, 0, stream>>>(Wv, wvt_h, wvt_l, 128, 128);
    wprep_k<<<dim3(4, 16, 6), 256, 0, stream>>>(ffW1, w1t_h, w1t_l, 128, 512);
    wprep_k<<<dim3(16, 4, 6), 256, 0, stream>>>(ffW2, w2t_h, w2t_l, 512, 128);
    wprep_k<<<dim3(4, 4, 1), 256, 0, stream>>>(dWk, dkt_h, dkt_l, 128, 128);
    wprep_k<<<dim3(4, 4, 1), 256, 0, stream>>>(dWv, dvt_h, dvt_l, 128, 128);

    embed_k<<<16384, 256, 0, stream>>>(data, emb_W, emb_b, xh, xl);

    for (int l = 0; l < L_; ++l) {
        Q3 q3{};
        q3.A0 = xh; q3.A1 = xl;
        q3.qh = wqt_h + l * 16384; q3.ql = wqt_l + l * 16384;
        q3.vh = wvt_h + l * 16384; q3.vl = wvt_l + l * 16384;
        q3.kh = wkt_h + l * 16384; q3.kl = wkt_l + l * 16384;
        q3.sq16 = sq16; q3.y2t = y2t;
        qvk3_k<<<512, 256, 0, stream>>>(q3);

        AP2 ap{};
        ap.A0 = dist; ap.B0 = y2t; ap.sq = sq16; ap.gh = gh; ap.gl = gl;
        ap.s1 = log_scale; ap.s2 = aft_alpha; ap.s2i = l;
        aft2_k<1, 1><<<512, 256, 0, stream>>>(ap);

        inorm_k<1><<<dim3(B_, 8), 256, 0, stream>>>(
            xh, xl, gh, gl, nullptr, n1_w + l * 128, n1_b + l * 128, hh, hl);

        F12 f12{};
        f12.A0 = hh; f12.A1 = hl;
        f12.w1h = w1t_h + l * 65536; f12.w1l = w1t_l + l * 65536;
        f12.w2h = w2t_h + l * 65536; f12.w2l = w2t_l + l * 65536;
        f12.b1 = ffb1 + l * 512; f12.b2 = ffb2 + l * 128;
        f12.of = ff2;
        ffn12_k<<<512, 512, 0, stream>>>(f12);

        inorm_k<2><<<dim3(B_, 8), 256, 0, stream>>>(
            hh, hl, nullptr, nullptr, ff2, n2_w + l * 128, n2_b + l * 128, xh, xl);
    }

    // ---- decoder ---- (enc = xh/xl)
    {
        QV qv{};
        qv.A0 = xh; qv.A1 = xl;
        qv.vh = dvt_h; qv.vl = dvt_l;
        qv.kh = dkt_h; qv.kl = dkt_l;
        qv.y2t = y2t;
        qvk_vk_k<<<512, 256, 0, stream>>>(qv);
        gq_k<<<B_, 512, 0, stream>>>(xh, xl, dWq, gq);

        AP2 ap{};
        ap.A0 = cur_dist; ap.A1 = ninf; ap.B0 = y2t; ap.gh = gh; ap.gl = gl;
        ap.s1 = log_scale; ap.s2 = dec_alpha; ap.s2i = 0;
        aft2_k<2, 0><<<512, 256, 0, stream>>>(ap);

        dec_aft_k<<<16384, 256, 0, stream>>>(gq, capacity, dWq, gh, gl, hh, hl);

        SP2 sp{};
        sp.A0 = hh; sp.A1 = hl; sp.B0 = xh; sp.B1 = xl;
        sp.out = out; sp.cd = cur_dist; sp.cm = ninf;
        sp.s1 = log_scale; sp.s2 = p_alpha;
        score_sm_k<<<512, 256, 0, stream>>>(sp);
    }
}

// Round 4
// 1131.496 us; speedup vs baseline: 1.0587x; 1.0587x over previous
//
#include <hip/hip_runtime.h>
#include <math.h>

#define B_ 64
#define N_ 512
#define P_ 512
#define E_ 128
#define F_ 512
#define L_ 6
#define SQRT_E_INV 0.08838834764831843f

typedef unsigned short u16;
typedef __attribute__((ext_vector_type(8))) short bf8;
typedef __attribute__((ext_vector_type(16))) float f16v;

__device__ inline u16 bf16r(float f) {
    unsigned u = __float_as_uint(f);
    u += 0x7fffu + ((u >> 16) & 1u);
    return (u16)(u >> 16);
}
__device__ inline float bf2f(u16 h) { return __uint_as_float((unsigned)h << 16); }

#define MFMA(a, b, c) __builtin_amdgcn_mfma_f32_32x32x16_bf16(a, b, c, 0, 0, 0)

// ===========================================================================
// qvk3_k: fused q/v/k for encoder layers. Tile 64 rows x 128 cols, K=128.
// ===========================================================================
struct Q3 {
    const u16 *A0, *A1;
    const u16 *qh, *ql, *vh, *vl, *kh, *kl;
    u16 *sq16, *y2t;
};

__launch_bounds__(256, 2) __global__ void qvk3_k(Q3 p)
{
    const int tid = threadIdx.x;
    const int lane = tid & 63, wv = tid >> 6;
    const int wm = wv & 1, wn = wv >> 1;
    const int ln = lane & 31, hk = lane >> 5;
    const int row0 = blockIdx.x * 64;

    __shared__ __align__(16) u16 As[2][64][40];
    __shared__ __align__(16) u16 Bs[6][128][40];

    f16v aq[2], av[2], ak[2];
#pragma unroll
    for (int nt = 0; nt < 2; ++nt)
#pragma unroll
        for (int q = 0; q < 16; ++q) { aq[nt][q] = 0.f; av[nt][q] = 0.f; ak[nt][q] = 0.f; }

    const int r = tid >> 2, kq = tid & 3;
    for (int k0 = 0; k0 < 128; k0 += 32) {
        size_t ga = (size_t)(row0 + r) * 128 + k0 + kq * 8;
        *(uint4*)&As[0][r][kq * 8] = *(const uint4*)(p.A0 + ga);
        *(uint4*)&As[1][r][kq * 8] = *(const uint4*)(p.A1 + ga);
#pragma unroll
        for (int i = 0; i < 2; ++i) {
            int s = tid + i * 256;
            int rb2 = s >> 2, q = s & 3;
            size_t gb = (size_t)rb2 * 128 + k0 + q * 8;
            *(uint4*)&Bs[0][rb2][q * 8] = *(const uint4*)(p.qh + gb);
            *(uint4*)&Bs[1][rb2][q * 8] = *(const uint4*)(p.ql + gb);
            *(uint4*)&Bs[2][rb2][q * 8] = *(const uint4*)(p.vh + gb);
            *(uint4*)&Bs[3][rb2][q * 8] = *(const uint4*)(p.vl + gb);
            *(uint4*)&Bs[4][rb2][q * 8] = *(const uint4*)(p.kh + gb);
            *(uint4*)&Bs[5][rb2][q * 8] = *(const uint4*)(p.kl + gb);
        }
        __syncthreads();
#pragma unroll
        for (int s = 0; s < 2; ++s) {
            bf8 ah = *(const bf8*)&As[0][wm * 32 + ln][s * 16 + hk * 8];
            bf8 al = *(const bf8*)&As[1][wm * 32 + ln][s * 16 + hk * 8];
#pragma unroll
            for (int nt = 0; nt < 2; ++nt) {
                const int br = wn * 64 + nt * 32 + ln, sc = s * 16 + hk * 8;
                bf8 bqh = *(const bf8*)&Bs[0][br][sc];
                bf8 bql = *(const bf8*)&Bs[1][br][sc];
                bf8 bvh = *(const bf8*)&Bs[2][br][sc];
                bf8 bvl = *(const bf8*)&Bs[3][br][sc];
                bf8 bkh = *(const bf8*)&Bs[4][br][sc];
                bf8 bkl = *(const bf8*)&Bs[5][br][sc];
                aq[nt] = MFMA(ah, bqh, aq[nt]);
                aq[nt] = MFMA(ah, bql, aq[nt]);
                aq[nt] = MFMA(al, bqh, aq[nt]);
                av[nt] = MFMA(ah, bvh, av[nt]);
                av[nt] = MFMA(ah, bvl, av[nt]);
                av[nt] = MFMA(al, bvh, av[nt]);
                ak[nt] = MFMA(ah, bkh, ak[nt]);
                ak[nt] = MFMA(ah, bkl, ak[nt]);
                ak[nt] = MFMA(al, bkh, ak[nt]);
            }
        }
        __syncthreads();
    }

#pragma unroll
    for (int nt = 0; nt < 2; ++nt) {
        int gn = wn * 64 + nt * 32 + ln;
#pragma unroll
        for (int g = 0; g < 4; ++g) {
            int rb = row0 + wm * 32 + g * 8 + hk * 4;
            int bb = rb >> 9, nb = rb & 511;
            u16 pe[4], pv[4];
#pragma unroll
            for (int rr = 0; rr < 4; ++rr) {
                float vq = aq[nt][g * 4 + rr];
                p.sq16[(size_t)(rb + rr) * 128 + gn] =
                    bf16r(1.f / (1.f + __expf(-vq)));
                u16 hv = bf16r(av[nt][g * 4 + rr]);
                u16 he = bf16r(__expf(ak[nt][g * 4 + rr]));
                pe[rr] = he;
                pv[rr] = bf16r(bf2f(hv) * bf2f(he));
            }
            uint2 ue, uv;
            ue.x = pe[0] | ((unsigned)pe[1] << 16);
            ue.y = pe[2] | ((unsigned)pe[3] << 16);
            uv.x = pv[0] | ((unsigned)pv[1] << 16);
            uv.y = pv[2] | ((unsigned)pv[3] << 16);
            *(uint2*)(p.y2t + (size_t)bb * 131072 + (size_t)gn * 512 + nb) = uv;
            *(uint2*)(p.y2t + (size_t)bb * 131072 + (size_t)(128 + gn) * 512 + nb) = ue;
        }
    }
}

// ===========================================================================
// qvk_vk_k: decoder v/k (no q).
// ===========================================================================
struct QV {
    const u16 *A0, *A1;
    const u16 *vh, *vl, *kh, *kl;
    u16* y2t;
};

__launch_bounds__(256, 3) __global__ void qvk_vk_k(QV p)
{
    const int tid = threadIdx.x;
    const int lane = tid & 63, wv = tid >> 6;
    const int wm = wv & 1, wn = wv >> 1;
    const int ln = lane & 31, hk = lane >> 5;
    const int row0 = blockIdx.x * 64;

    __shared__ __align__(16) u16 As[2][64][40];
    __shared__ __align__(16) u16 Bs[4][128][40];

    f16v av[2], ak[2];
#pragma unroll
    for (int nt = 0; nt < 2; ++nt)
#pragma unroll
        for (int q = 0; q < 16; ++q) { av[nt][q] = 0.f; ak[nt][q] = 0.f; }

    const int r = tid >> 2, kq = tid & 3;
    for (int k0 = 0; k0 < 128; k0 += 32) {
        size_t ga = (size_t)(row0 + r) * 128 + k0 + kq * 8;
        *(uint4*)&As[0][r][kq * 8] = *(const uint4*)(p.A0 + ga);
        *(uint4*)&As[1][r][kq * 8] = *(const uint4*)(p.A1 + ga);
#pragma unroll
        for (int i = 0; i < 2; ++i) {
            int s = tid + i * 256;
            int rb2 = s >> 2, q = s & 3;
            size_t gb = (size_t)rb2 * 128 + k0 + q * 8;
            *(uint4*)&Bs[0][rb2][q * 8] = *(const uint4*)(p.vh + gb);
            *(uint4*)&Bs[1][rb2][q * 8] = *(const uint4*)(p.vl + gb);
            *(uint4*)&Bs[2][rb2][q * 8] = *(const uint4*)(p.kh + gb);
            *(uint4*)&Bs[3][rb2][q * 8] = *(const uint4*)(p.kl + gb);
        }
        __syncthreads();
#pragma unroll
        for (int s = 0; s < 2; ++s) {
            bf8 ah = *(const bf8*)&As[0][wm * 32 + ln][s * 16 + hk * 8];
            bf8 al = *(const bf8*)&As[1][wm * 32 + ln][s * 16 + hk * 8];
#pragma unroll
            for (int nt = 0; nt < 2; ++nt) {
                const int br = wn * 64 + nt * 32 + ln, sc = s * 16 + hk * 8;
                bf8 bvh = *(const bf8*)&Bs[0][br][sc];
                bf8 bvl = *(const bf8*)&Bs[1][br][sc];
                bf8 bkh = *(const bf8*)&Bs[2][br][sc];
                bf8 bkl = *(const bf8*)&Bs[3][br][sc];
                av[nt] = MFMA(ah, bvh, av[nt]);
                av[nt] = MFMA(ah, bvl, av[nt]);
                av[nt] = MFMA(al, bvh, av[nt]);
                ak[nt] = MFMA(ah, bkh, ak[nt]);
                ak[nt] = MFMA(ah, bkl, ak[nt]);
                ak[nt] = MFMA(al, bkh, ak[nt]);
            }
        }
        __syncthreads();
    }

#pragma unroll
    for (int nt = 0; nt < 2; ++nt) {
        int gn = wn * 64 + nt * 32 + ln;
#pragma unroll
        for (int g = 0; g < 4; ++g) {
            int rb = row0 + wm * 32 + g * 8 + hk * 4;
            int bb = rb >> 9, nb = rb & 511;
            u16 pe[4], pv[4];
#pragma unroll
            for (int rr = 0; rr < 4; ++rr) {
                u16 hv = bf16r(av[nt][g * 4 + rr]);
                u16 he = bf16r(__expf(ak[nt][g * 4 + rr]));
                pe[rr] = he;
                pv[rr] = bf16r(bf2f(hv) * bf2f(he));
            }
            uint2 ue, uv;
            ue.x = pe[0] | ((unsigned)pe[1] << 16);
            ue.y = pe[2] | ((unsigned)pe[3] << 16);
            uv.x = pv[0] | ((unsigned)pv[1] << 16);
            uv.y = pv[2] | ((unsigned)pv[3] << 16);
            *(uint2*)(p.y2t + (size_t)bb * 131072 + (size_t)gn * 512 + nb) = uv;
            *(uint2*)(p.y2t + (size_t)bb * 131072 + (size_t)(128 + gn) * 512 + nb) = ue;
        }
    }
}

// ===========================================================================
// aft2_k: AFT aggregation, num+den in one block. A-plane is bf16:
// OPA1: A = exp(ascale * a16)   (encoder, a16 = bf16(dist))
// OPA3: A = exp(a16)            (decoder, a16 = bf16(as*cd + ninf) prefused)
// ===========================================================================
struct AP2 {
    const u16 *A16;
    const u16 *B0, *sq;
    u16 *gh, *gl;
    const float *s1, *s2; int s2i;
};

template <int OPA, int SG>
__launch_bounds__(256, 3) __global__ void aft2_k(AP2 p)
{
    const int tid = threadIdx.x;
    const int lane = tid & 63, wv = tid >> 6;
    const int wm = wv & 1, wn = wv >> 1;
    const int ln = lane & 31, hk = lane >> 5;

    const int id = blockIdx.x;
    const int xcd = id & 7, slot = id >> 3;
    const int bz = xcd * 8 + (slot >> 3);
    const int row0 = (slot & 7) * 64;

    __shared__ __align__(16) u16 As[2][64][40];
    __shared__ __align__(16) u16 Bs[2][256][40];

    f16v acc[4];
#pragma unroll
    for (int j = 0; j < 4; ++j)
#pragma unroll
        for (int q = 0; q < 16; ++q) acc[j][q] = 0.f;

    const float ascale = (OPA == 1) ? p.s1[0] * p.s2[p.s2i] : 0.f;
    const u16* Af = p.A16 + (size_t)bz * 262144 + (size_t)row0 * 512;
    const u16* Bb = p.B0 + (size_t)bz * 131072;

    const int r = tid >> 2, kq = tid & 3;
    uint4 va;
    uint4 vb[4];

#define AFT_LOAD(K0)                                                          \
    {                                                                         \
        va = *(const uint4*)(Af + (size_t)r * 512 + (K0) + kq * 8);           \
        size_t gb = (size_t)tid * 512 + (K0);                                 \
        _Pragma("unroll") for (int q = 0; q < 4; ++q)                         \
            vb[q] = *(const uint4*)(Bb + gb + q * 8);                         \
    }

#define AFT_WRITE(BUF)                                                        \
    {                                                                         \
        u16 a8[8];                                                            \
        *(uint4*)a8 = va;                                                     \
        float f[8];                                                           \
        _Pragma("unroll") for (int j = 0; j < 8; ++j) {                       \
            float t = bf2f(a8[j]);                                            \
            if (OPA == 1) t *= ascale;                                        \
            f[j] = __expf(t);                                                 \
        }                                                                     \
        uint4 pk;                                                             \
        pk.x = bf16r(f[0]) | ((unsigned)bf16r(f[1]) << 16);                   \
        pk.y = bf16r(f[2]) | ((unsigned)bf16r(f[3]) << 16);                   \
        pk.z = bf16r(f[4]) | ((unsigned)bf16r(f[5]) << 16);                   \
        pk.w = bf16r(f[6]) | ((unsigned)bf16r(f[7]) << 16);                   \
        *(uint4*)&As[BUF][r][kq * 8] = pk;                                    \
        _Pragma("unroll") for (int q = 0; q < 4; ++q)                         \
            *(uint4*)&Bs[BUF][tid][q * 8] = vb[q];                            \
    }

#define AFT_COMPUTE(BUF)                                                      \
    {                                                                         \
        _Pragma("unroll") for (int s = 0; s < 2; ++s) {                       \
            bf8 ah = *(const bf8*)&As[BUF][wm * 32 + ln][s * 16 + hk * 8];    \
            _Pragma("unroll") for (int j = 0; j < 4; ++j) {                   \
                int br = ((j >> 1) << 7) + wn * 64 + ((j & 1) << 5) + ln;     \
                bf8 bh = *(const bf8*)&Bs[BUF][br][s * 16 + hk * 8];          \
                acc[j] = MFMA(ah, bh, acc[j]);                                \
            }                                                                 \
        }                                                                     \
    }

    AFT_LOAD(0);
    AFT_WRITE(0);
    __syncthreads();

    int cur = 0;
    for (int k0 = 32; k0 < 512; k0 += 32) {
        AFT_LOAD(k0);
        AFT_COMPUTE(cur);
        AFT_WRITE(cur ^ 1);
        __syncthreads();
        cur ^= 1;
    }
    AFT_COMPUTE(cur);

#undef AFT_LOAD
#undef AFT_WRITE
#undef AFT_COMPUTE

    const u16* sqb = SG ? (p.sq + (size_t)bz * 65536) : (const u16*)0;
    u16* ghb = p.gh + (size_t)bz * 65536;
    u16* glb = p.gl + (size_t)bz * 65536;
#pragma unroll
    for (int j = 0; j < 2; ++j) {
        int e = wn * 64 + j * 32 + ln;
#pragma unroll
        for (int g = 0; g < 4; ++g) {
#pragma unroll
            for (int rr = 0; rr < 4; ++rr) {
                int row = row0 + wm * 32 + g * 8 + hk * 4 + rr;
                float num = acc[j][g * 4 + rr];
                float den = acc[j + 2][g * 4 + rr];
                float pv = num / den;
                if (SG) pv *= bf2f(sqb[(size_t)row * 128 + e]);
                u16 hi = bf16r(pv);
                ghb[(size_t)row * 128 + e] = hi;
                glb[(size_t)row * 128 + e] = bf16r(pv - bf2f(hi));
            }
        }
    }
}

// ===========================================================================
// ffn12_k v2: fused FFN, double-buffered reg-staged weight pipeline.
// 512 threads (2x4 waves), 64 rows/block, grid 512. LDS: Ws dbuf 72 KB +
// ff1c 68 KB. Phase1: 8 (ct,kc) steps; phase2: 8 K-steps; W2 step 0
// prefetched during phase1's last step.
// ===========================================================================
struct F12 {
    const u16 *A0, *A1;
    const u16 *w1h, *w1l;      // [512][128]
    const u16 *w2h, *w2l;      // [128][512]
    const float *b1, *b2;
    float* of;
};

__launch_bounds__(512, 2) __global__ void ffn12_k(F12 p)
{
    const int tid = threadIdx.x;
    const int lane = tid & 63, wv = tid >> 6;
    const int wm = wv & 1, wn = wv >> 1;
    const int ln = lane & 31, hk = lane >> 5;
    const int row0 = blockIdx.x * 64;

    __shared__ __align__(16) u16 Ws[2][2][128][72];
    __shared__ __align__(16) u16 ff1c[4][64][136];

    bf8 ar0[8], ar1[8];
    {
        const size_t arow = (size_t)(row0 + wm * 32 + ln) * 128;
#pragma unroll
        for (int s = 0; s < 8; ++s) {
            ar0[s] = *(const bf8*)(p.A0 + arow + s * 16 + hk * 8);
            ar1[s] = *(const bf8*)(p.A1 + arow + s * 16 + hk * 8);
        }
    }

    const int lcol = wn * 32 + ln;
    const int sc_ = tid >> 3, sq_ = tid & 7;   // staging: col, 8-u16 quad
    uint4 wr[2][2];

#define F_LOAD1(CT, KC)                                                       \
    {                                                                         \
        _Pragma("unroll") for (int pl = 0; pl < 2; ++pl) {                    \
            const u16* src = pl ? p.w1l : p.w1h;                              \
            _Pragma("unroll") for (int it = 0; it < 2; ++it) {                \
                int c = sc_ + it * 64;                                        \
                wr[pl][it] = *(const uint4*)(src +                            \
                    (size_t)((CT) * 128 + c) * 128 + (KC) * 64 + sq_ * 8);    \
            }                                                                 \
        }                                                                     \
    }

#define F_LOAD2(J)                                                            \
    {                                                                         \
        _Pragma("unroll") for (int pl = 0; pl < 2; ++pl) {                    \
            const u16* src = pl ? p.w2l : p.w2h;                              \
            _Pragma("unroll") for (int it = 0; it < 2; ++it) {                \
                int c = sc_ + it * 64;                                        \
                wr[pl][it] = *(const uint4*)(src +                            \
                    (size_t)c * 512 + (J) * 64 + sq_ * 8);                    \
            }                                                                 \
        }                                                                     \
    }

#define F_STORE(BUF)                                                          \
    {                                                                         \
        _Pragma("unroll") for (int pl = 0; pl < 2; ++pl)                      \
            _Pragma("unroll") for (int it = 0; it < 2; ++it)                  \
                *(uint4*)&Ws[BUF][pl][sc_ + it * 64][sq_ * 8] = wr[pl][it];   \
    }

    // ---- phase 1 ----
    F_LOAD1(0, 0);
    F_STORE(0);
    __syncthreads();
    int buf = 0;
    f16v a0, a1, a2;
#pragma unroll
    for (int st = 0; st < 8; ++st) {
        const int ct = st >> 1, kc = st & 1;
        if (st < 7) { F_LOAD1((st + 1) >> 1, (st + 1) & 1); }
        else        { F_LOAD2(0); }
        if (kc == 0) {
#pragma unroll
            for (int q = 0; q < 16; ++q) { a0[q] = 0.f; a1[q] = 0.f; a2[q] = 0.f; }
        }
#pragma unroll
        for (int s = 0; s < 4; ++s) {
            bf8 bh = *(const bf8*)&Ws[buf][0][lcol][s * 16 + hk * 8];
            bf8 bl = *(const bf8*)&Ws[buf][1][lcol][s * 16 + hk * 8];
            a0 = MFMA(ar0[kc * 4 + s], bh, a0);
            a1 = MFMA(ar0[kc * 4 + s], bl, a1);
            a2 = MFMA(ar1[kc * 4 + s], bh, a2);
        }
        if (kc == 1) {
            float bv = p.b1[ct * 128 + lcol];
#pragma unroll
            for (int g = 0; g < 4; ++g)
#pragma unroll
                for (int rr = 0; rr < 4; ++rr) {
                    int lr = wm * 32 + g * 8 + hk * 4 + rr;
                    float v = a0[g * 4 + rr] + a1[g * 4 + rr] + a2[g * 4 + rr] + bv;
                    ff1c[ct][lr][lcol] = bf16r(fmaxf(v, 0.f));
                }
        }
        F_STORE(buf ^ 1);
        __syncthreads();
        buf ^= 1;
    }

    // ---- phase 2 ----
    f16v c0, c1;
#pragma unroll
    for (int q = 0; q < 16; ++q) { c0[q] = 0.f; c1[q] = 0.f; }
#pragma unroll
    for (int j = 0; j < 8; ++j) {
        if (j < 7) F_LOAD2(j + 1);
#pragma unroll
        for (int s = 0; s < 4; ++s) {
            bf8 af = *(const bf8*)&ff1c[j >> 1][wm * 32 + ln]
                                      [(j & 1) * 64 + s * 16 + hk * 8];
            bf8 bh = *(const bf8*)&Ws[buf][0][lcol][s * 16 + hk * 8];
            bf8 bl = *(const bf8*)&Ws[buf][1][lcol][s * 16 + hk * 8];
            c0 = MFMA(af, bh, c0);
            c1 = MFMA(af, bl, c1);
        }
        if (j < 7) {
            F_STORE(buf ^ 1);
            __syncthreads();
            buf ^= 1;
        }
    }

#undef F_LOAD1
#undef F_LOAD2
#undef F_STORE

    float bv = p.b2[lcol];
#pragma unroll
    for (int g = 0; g < 4; ++g)
#pragma unroll
        for (int rr = 0; rr < 4; ++rr) {
            int rb = row0 + wm * 32 + g * 8 + hk * 4 + rr;
            p.of[(size_t)rb * 128 + lcol] = c0[g * 4 + rr] + c1[g * 4 + rr] + bv;
        }
}

// ===========================================================================
// score_sm_k v2: fused score+softmax. 512 threads (2x4 waves), 64 rows x
// 512 cols, accs[4] (64 VGPR), cd/cm prefetched per ct chunk. 2 blocks/CU.
// ===========================================================================
struct SP2 {
    const u16 *A0, *A1, *B0, *B1;
    float* out;
    const float *cd, *cm;
    const float *s1, *s2;
};

__launch_bounds__(512, 4) __global__ void score_sm_k(SP2 p)
{
    const int tid = threadIdx.x;
    const int lane = tid & 63, wv = tid >> 6;
    const int wm = wv & 1, wn = wv >> 1;
    const int ln = lane & 31, hk = lane >> 5;

    const int id = blockIdx.x;
    const int xcd = id & 7, s_ = id >> 3;
    const int bz = xcd * 8 + (s_ & 7);
    const int row0 = (s_ >> 3) * 64;

    __shared__ __align__(16) u16 As[2][64][136];
    __shared__ __align__(16) u16 Bs[2][128][72];
    __shared__ float rs[4][64];

    // stage A once (K=128, both planes)
#pragma unroll
    for (int i = 0; i < 4; ++i) {
        int idx = tid + i * 512;
        int pl = idx >> 10, rem = idx & 1023;
        int row = rem >> 4, q = rem & 15;
        const u16* src = pl ? p.A1 : p.A0;
        *(uint4*)&As[pl][row][q * 8] =
            *(const uint4*)(src + ((size_t)bz * 512 + row0 + row) * 128 + q * 8);
    }

    const float sp = p.s1[0] * p.s2[0];
    f16v accs[4];

#pragma unroll
    for (int ct = 0; ct < 4; ++ct) {
        const int gn = ct * 128 + wn * 32 + ln;
        // prefetch epilogue operands (latency hides under the MFMA phases)
        float cdv[16], cmv[16];
#pragma unroll
        for (int g = 0; g < 4; ++g)
#pragma unroll
            for (int rr = 0; rr < 4; ++rr) {
                int grow = row0 + wm * 32 + g * 8 + hk * 4 + rr;
                size_t ix = (size_t)bz * 262144 + (size_t)grow * 512 + gn;
                cdv[g * 4 + rr] = p.cd[ix];
                cmv[g * 4 + rr] = p.cm[ix];
            }
#pragma unroll
        for (int q = 0; q < 16; ++q) accs[ct][q] = 0.f;

#pragma unroll
        for (int kh = 0; kh < 2; ++kh) {
            const int kc = kh * 64;
#pragma unroll
            for (int i = 0; i < 4; ++i) {
                int idx = tid + i * 512;
                int pl = idx >> 10, rem = idx & 1023;
                int row = rem >> 3, q = rem & 7;
                const u16* src = pl ? p.B1 : p.B0;
                *(uint4*)&Bs[pl][row][q * 8] =
                    *(const uint4*)(src + ((size_t)bz * 512 + ct * 128 + row) * 128
                                    + kc + q * 8);
            }
            __syncthreads();
#pragma unroll
            for (int s = 0; s < 4; ++s) {
                bf8 ah = *(const bf8*)&As[0][wm * 32 + ln][kc + s * 16 + hk * 8];
                bf8 al = *(const bf8*)&As[1][wm * 32 + ln][kc + s * 16 + hk * 8];
                bf8 bh = *(const bf8*)&Bs[0][wn * 32 + ln][s * 16 + hk * 8];
                bf8 bl = *(const bf8*)&Bs[1][wn * 32 + ln][s * 16 + hk * 8];
                accs[ct] = MFMA(ah, bh, accs[ct]);
                accs[ct] = MFMA(ah, bl, accs[ct]);
                accs[ct] = MFMA(al, bh, accs[ct]);
            }
            __syncthreads();
        }

        // epilogue: score -> exp, kept in accs
#pragma unroll
        for (int i = 0; i < 16; ++i) {
            float sc = fmaf(accs[ct][i], SQRT_E_INV, sp * cdv[i]);
            float e2 = __expf(2.f * sc);
            float th = 1.f - 2.f / (e2 + 1.f);
            accs[ct][i] = __expf(10.f * th + cmv[i]);
        }
    }

    // row sums
    float rsum[16];
#pragma unroll
    for (int i = 0; i < 16; ++i)
        rsum[i] = accs[0][i] + accs[1][i] + accs[2][i] + accs[3][i];
#pragma unroll
    for (int i = 0; i < 16; ++i) {
#pragma unroll
        for (int o = 1; o < 32; o <<= 1) rsum[i] += __shfl_xor(rsum[i], o);
    }
    __syncthreads();
    if (ln == 0) {
#pragma unroll
        for (int i = 0; i < 16; ++i) {
            int lr = wm * 32 + (i >> 2) * 8 + hk * 4 + (i & 3);
            rs[wn][lr] = rsum[i];
        }
    }
    __syncthreads();
    float invr[16];
#pragma unroll
    for (int i = 0; i < 16; ++i) {
        int lr = wm * 32 + (i >> 2) * 8 + hk * 4 + (i & 3);
        invr[i] = 1.f / (rs[0][lr] + rs[1][lr] + rs[2][lr] + rs[3][lr]);
    }

#pragma unroll
    for (int ct = 0; ct < 4; ++ct) {
        int gn = ct * 128 + wn * 32 + ln;
#pragma unroll
        for (int g = 0; g < 4; ++g)
#pragma unroll
            for (int rr = 0; rr < 4; ++rr) {
                int grow = row0 + wm * 32 + g * 8 + hk * 4 + rr;
                size_t ix = (size_t)bz * 262144 + (size_t)grow * 512 + gn;
                p.out[ix] = accs[ct][g * 4 + rr] * invr[g * 4 + rr];
            }
    }
}

// ===========================================================================
// InstanceNorm over nodes, residual fused.
// ===========================================================================
template <int MODE>
__launch_bounds__(256) __global__ void inorm_k(
    const u16* __restrict__ ah, const u16* __restrict__ al,
    const u16* __restrict__ g0, const u16* __restrict__ g1,
    const float* __restrict__ f1,
    const float* __restrict__ nw, const float* __restrict__ nbv,
    u16* __restrict__ oh, u16* __restrict__ ol)
{
    const int bb = blockIdx.x, e0 = blockIdx.y * 16;
    const int tid = threadIdx.x, el = tid & 3, no = tid >> 2;
    const size_t base = (size_t)bb * N_ * E_ + e0 + el * 4;

    float4 vals[8];
    float s1x = 0, s1y = 0, s1z = 0, s1w = 0;
    float s2x = 0, s2y = 0, s2z = 0, s2w = 0;
#pragma unroll
    for (int i = 0; i < 8; ++i) {
        int n = no * 8 + i;
        size_t ad = base + (size_t)n * E_;
        uint2 h2 = *(const uint2*)(ah + ad);
        uint2 l2 = *(const uint2*)(al + ad);
        float x0 = bf2f((u16)h2.x) + bf2f((u16)l2.x);
        float x1 = bf2f((u16)(h2.x >> 16)) + bf2f((u16)(l2.x >> 16));
        float x2 = bf2f((u16)h2.y) + bf2f((u16)l2.y);
        float x3 = bf2f((u16)(h2.y >> 16)) + bf2f((u16)(l2.y >> 16));
        float4 v;
        if (MODE == 1) {
            uint2 a2 = *(const uint2*)(g0 + ad);
            uint2 b2 = *(const uint2*)(g1 + ad);
            v.x = x0 + bf2f((u16)a2.x) + bf2f((u16)b2.x);
            v.y = x1 + bf2f((u16)(a2.x >> 16)) + bf2f((u16)(b2.x >> 16));
            v.z = x2 + bf2f((u16)a2.y) + bf2f((u16)b2.y);
            v.w = x3 + bf2f((u16)(a2.y >> 16)) + bf2f((u16)(b2.y >> 16));
        } else {
            float4 ff = *(const float4*)(f1 + ad);
            v.x = x0 + ff.x; v.y = x1 + ff.y; v.z = x2 + ff.z; v.w = x3 + ff.w;
        }
        vals[i] = v;
        s1x += v.x; s1y += v.y; s1z += v.z; s1w += v.w;
        s2x = fmaf(v.x, v.x, s2x); s2y = fmaf(v.y, v.y, s2y);
        s2z = fmaf(v.z, v.z, s2z); s2w = fmaf(v.w, v.w, s2w);
    }

    __shared__ float4 r1[256], r2[256];
    r1[tid] = make_float4(s1x, s1y, s1z, s1w);
    r2[tid] = make_float4(s2x, s2y, s2z, s2w);
    __syncthreads();
    for (int s = 128; s >= 4; s >>= 1) {
        if (tid < s) {
            float4 u = r1[tid], w = r1[tid + s];
            r1[tid] = make_float4(u.x + w.x, u.y + w.y, u.z + w.z, u.w + w.w);
            float4 pq = r2[tid], q = r2[tid + s];
            r2[tid] = make_float4(pq.x + q.x, pq.y + q.y, pq.z + q.z, pq.w + q.w);
        }
        __syncthreads();
    }
    __shared__ float4 mu_s[4], rs_s[4];
    if (tid < 4) {
        float4 m = r1[tid], q = r2[tid];
        m.x *= (1.f / N_); m.y *= (1.f / N_); m.z *= (1.f / N_); m.w *= (1.f / N_);
        q.x *= (1.f / N_); q.y *= (1.f / N_); q.z *= (1.f / N_); q.w *= (1.f / N_);
        float4 rsq;
        rsq.x = rsqrtf(q.x - m.x * m.x + 1e-5f);
        rsq.y = rsqrtf(q.y - m.y * m.y + 1e-5f);
        rsq.z = rsqrtf(q.z - m.z * m.z + 1e-5f);
        rsq.w = rsqrtf(q.w - m.w * m.w + 1e-5f);
        mu_s[tid] = m; rs_s[tid] = rsq;
    }
    __syncthreads();
    float4 mu = mu_s[el], rsq = rs_s[el];
    float4 w4 = *(const float4*)(nw + e0 + el * 4);
    float4 b4 = *(const float4*)(nbv + e0 + el * 4);
#pragma unroll
    for (int i = 0; i < 8; ++i) {
        size_t ad = base + (size_t)(no * 8 + i) * E_;
        float4 v = vals[i];
        v.x = fmaf((v.x - mu.x) * rsq.x, w4.x, b4.x);
        v.y = fmaf((v.y - mu.y) * rsq.y, w4.y, b4.y);
        v.z = fmaf((v.z - mu.z) * rsq.z, w4.z, b4.z);
        v.w = fmaf((v.w - mu.w) * rsq.w, w4.w, b4.w);
        u16 h0 = bf16r(v.x), h1 = bf16r(v.y), h2v = bf16r(v.z), h3 = bf16r(v.w);
        u16 l0 = bf16r(v.x - bf2f(h0)), l1 = bf16r(v.y - bf2f(h1));
        u16 l2v = bf16r(v.z - bf2f(h2v)), l3 = bf16r(v.w - bf2f(h3));
        uint2 ph, pl;
        ph.x = h0 | ((unsigned)h1 << 16); ph.y = h2v | ((unsigned)h3 << 16);
        pl.x = l0 | ((unsigned)l1 << 16); pl.y = l2v | ((unsigned)l3 << 16);
        *(uint2*)(oh + ad) = ph;
        *(uint2*)(ol + ad) = pl;
    }
}

// ===========================================================================
__global__ void wprep_k(const float* __restrict__ W, u16* __restrict__ Th,
                        u16* __restrict__ Tl, int K, int N)
{
    const int z = blockIdx.z;
    const float* Wz = W + (size_t)z * K * N;
    u16* Hh = Th + (size_t)z * K * N;
    u16* Hl = Tl + (size_t)z * K * N;
    __shared__ float t[32][33];
    const int j = threadIdx.x & 31, i0 = threadIdx.x >> 5;
    const int k0 = blockIdx.x * 32, n0 = blockIdx.y * 32;
    for (int i = i0; i < 32; i += 8)
        t[i][j] = Wz[(size_t)(k0 + i) * N + n0 + j];
    __syncthreads();
    for (int i = i0; i < 32; i += 8) {
        float v = t[j][i];
        u16 h = bf16r(v);
        u16 l = bf16r(v - bf2f(h));
        size_t o = (size_t)(n0 + i) * K + k0 + j;
        Hh[o] = h; Hl[o] = l;
    }
}

// distprep_k: d16 = bf16(dist)   (8 elems/thread)
__global__ void distprep_k(const float* __restrict__ src, u16* __restrict__ dst)
{
    size_t i = ((size_t)blockIdx.x * 256 + threadIdx.x) * 8;
    float4 f0 = *(const float4*)(src + i);
    float4 f1 = *(const float4*)(src + i + 4);
    uint4 pk;
    pk.x = bf16r(f0.x) | ((unsigned)bf16r(f0.y) << 16);
    pk.y = bf16r(f0.z) | ((unsigned)bf16r(f0.w) << 16);
    pk.z = bf16r(f1.x) | ((unsigned)bf16r(f1.y) << 16);
    pk.w = bf16r(f1.z) | ((unsigned)bf16r(f1.w) << 16);
    *(uint4*)(dst + i) = pk;
}

// decprep_k: am16 = bf16(da*cd + ninf)
__global__ void decprep_k(const float* __restrict__ cd, const float* __restrict__ nf,
                          const float* __restrict__ s1, const float* __restrict__ s2,
                          u16* __restrict__ dst)
{
    const float da = s1[0] * s2[0];
    size_t i = ((size_t)blockIdx.x * 256 + threadIdx.x) * 8;
    float4 c0 = *(const float4*)(cd + i);
    float4 c1 = *(const float4*)(cd + i + 4);
    float4 m0 = *(const float4*)(nf + i);
    float4 m1 = *(const float4*)(nf + i + 4);
    uint4 pk;
    pk.x = bf16r(fmaf(da, c0.x, m0.x)) | ((unsigned)bf16r(fmaf(da, c0.y, m0.y)) << 16);
    pk.y = bf16r(fmaf(da, c0.z, m0.z)) | ((unsigned)bf16r(fmaf(da, c0.w, m0.w)) << 16);
    pk.z = bf16r(fmaf(da, c1.x, m1.x)) | ((unsigned)bf16r(fmaf(da, c1.y, m1.y)) << 16);
    pk.w = bf16r(fmaf(da, c1.z, m1.z)) | ((unsigned)bf16r(fmaf(da, c1.w, m1.w)) << 16);
    *(uint4*)(dst + i) = pk;
}

__global__ void embed_k(const float* __restrict__ data, const float* __restrict__ W,
                        const float* __restrict__ bias,
                        u16* __restrict__ xh, u16* __restrict__ xl)
{
    size_t idx = (size_t)blockIdx.x * 256 + threadIdx.x;
    int e = idx & 127;
    size_t bn = idx >> 7;
    float v = fmaf(data[bn * 2], W[e], fmaf(data[bn * 2 + 1], W[128 + e], bias[e]));
    u16 h = bf16r(v);
    xh[idx] = h;
    xl[idx] = bf16r(v - bf2f(h));
}

__launch_bounds__(512) __global__
void gq_k(const u16* __restrict__ xh, const u16* __restrict__ xl,
          const float* __restrict__ dWq, float* __restrict__ gq)
{
    int b = blockIdx.x;
    int tid = threadIdx.x;
    int e = tid & 127, qd = tid >> 7;
    float s = 0.f;
    for (int n = qd; n < N_; n += 4) {
        size_t ix = ((size_t)b * N_ + n) * E_ + e;
        s += bf2f(xh[ix]) + bf2f(xl[ix]);
    }
    __shared__ float part[512];
    __shared__ float gm[128];
    part[tid] = s;
    __syncthreads();
    if (tid < 128)
        gm[tid] = (part[tid] + part[tid + 128] + part[tid + 256] + part[tid + 384]) *
                  (1.f / N_);
    __syncthreads();
    if (tid < 128) {
        float acc = 0.f;
        for (int kk = 0; kk < 128; ++kk) acc = fmaf(gm[kk], dWq[kk * 128 + tid], acc);
        gq[b * 128 + tid] = acc;
    }
}

__global__ void dec_aft_k(const float* __restrict__ gq, const float* __restrict__ cap,
                          const float* __restrict__ dWq,
                          const u16* __restrict__ rh, const u16* __restrict__ rl,
                          u16* __restrict__ oh, u16* __restrict__ ol)
{
    size_t idx = (size_t)blockIdx.x * 256 + threadIdx.x;
    int e = idx & 127;
    size_t bp = idx >> 7;
    int b = (int)(bp >> 9);
    float q = fmaf(cap[bp], dWq[128 * 128 + e], gq[b * 128 + e]);
    float sg = 1.f / (1.f + __expf(-q));
    float v = sg * (bf2f(rh[idx]) + bf2f(rl[idx]));
    u16 h = bf16r(v);
    oh[idx] = h;
    ol[idx] = bf16r(v - bf2f(h));
}

// ===========================================================================
extern "C" void kernel_launch(void* const* d_in, const int* in_sizes, int n_in,
                              void* d_out, int out_size, void* d_ws, size_t ws_size,
                              hipStream_t stream)
{
    const float* data      = (const float*)d_in[0];
    const float* dist      = (const float*)d_in[1];
    const float* cur_dist  = (const float*)d_in[2];
    const float* capacity  = (const float*)d_in[3];
    const float* ninf      = (const float*)d_in[4];
    const float* log_scale = (const float*)d_in[5];
    const float* emb_W     = (const float*)d_in[6];
    const float* emb_b     = (const float*)d_in[7];
    const float* Wq        = (const float*)d_in[8];
    const float* Wk        = (const float*)d_in[9];
    const float* Wv        = (const float*)d_in[10];
    const float* aft_alpha = (const float*)d_in[11];
    const float* n1_w      = (const float*)d_in[12];
    const float* n1_b      = (const float*)d_in[13];
    const float* ffW1      = (const float*)d_in[14];
    const float* ffb1      = (const float*)d_in[15];
    const float* ffW2      = (const float*)d_in[16];
    const float* ffb2      = (const float*)d_in[17];
    const float* n2_w      = (const float*)d_in[18];
    const float* n2_b      = (const float*)d_in[19];
    const float* dWq       = (const float*)d_in[20];
    const float* dWk       = (const float*)d_in[21];
    const float* dWv       = (const float*)d_in[22];
    const float* dec_alpha = (const float*)d_in[23];
    const float* p_alpha   = (const float*)d_in[24];
    float* out = (float*)d_out;

    char* W = (char*)d_ws;
    size_t off = 0;
    auto take = [&](size_t n) { void* pp = W + off; off += (n + 255) & ~(size_t)255; return pp; };
    const size_t SZP = (size_t)B_ * N_ * E_ * 2;   // 8 MB bf16 plane

    u16* xh   = (u16*)take(SZP);
    u16* xl   = (u16*)take(SZP);
    u16* hh   = (u16*)take(SZP);
    u16* hl   = (u16*)take(SZP);
    u16* sq16 = (u16*)take(SZP);
    u16* gh   = (u16*)take(SZP);
    u16* gl   = (u16*)take(SZP);
    u16* y2t  = (u16*)take(2 * SZP);
    float* ff2 = (float*)take((size_t)B_ * N_ * E_ * 4);   // 16 MB fp32
    u16* d16  = (u16*)take((size_t)B_ * N_ * N_ * 2);      // 32 MB bf16 dist
    u16* wqt_h = (u16*)take(196608); u16* wqt_l = (u16*)take(196608);
    u16* wkt_h = (u16*)take(196608); u16* wkt_l = (u16*)take(196608);
    u16* wvt_h = (u16*)take(196608); u16* wvt_l = (u16*)take(196608);
    u16* w1t_h = (u16*)take(786432); u16* w1t_l = (u16*)take(786432);
    u16* w2t_h = (u16*)take(786432); u16* w2t_l = (u16*)take(786432);
    u16* dkt_h = (u16*)take(32768);  u16* dkt_l = (u16*)take(32768);
    u16* dvt_h = (u16*)take(32768);  u16* dvt_l = (u16*)take(32768);
    float* gq = (float*)take(32768);
    if (ws_size < off) return;

    u16* am16 = d16;   // decoder A-plane aliases d16 (dead after encoder)

    // ---- weight prep ----
    wprep_k<<<dim3(4, 4, 6), 256, 0, stream>>>(Wq, wqt_h, wqt_l, 128, 128);
    wprep_k<<<dim3(4, 4, 6), 256, 0, stream>>>(Wk, wkt_h, wkt_l, 128, 128);
    wprep_k<<<dim3(4, 4, 6), 256, 0, stream>>>(Wv, wvt_h, wvt_l, 128, 128);
    wprep_k<<<dim3(4, 16, 6), 256, 0, stream>>>(ffW1, w1t_h, w1t_l, 128, 512);
    wprep_k<<<dim3(16, 4, 6), 256, 0, stream>>>(ffW2, w2t_h, w2t_l, 512, 128);
    wprep_k<<<dim3(4, 4, 1), 256, 0, stream>>>(dWk, dkt_h, dkt_l, 128, 128);
    wprep_k<<<dim3(4, 4, 1), 256, 0, stream>>>(dWv, dvt_h, dvt_l, 128, 128);

    distprep_k<<<8192, 256, 0, stream>>>(dist, d16);
    embed_k<<<16384, 256, 0, stream>>>(data, emb_W, emb_b, xh, xl);

    for (int l = 0; l < L_; ++l) {
        Q3 q3{};
        q3.A0 = xh; q3.A1 = xl;
        q3.qh = wqt_h + l * 16384; q3.ql = wqt_l + l * 16384;
        q3.vh = wvt_h + l * 16384; q3.vl = wvt_l + l * 16384;
        q3.kh = wkt_h + l * 16384; q3.kl = wkt_l + l * 16384;
        q3.sq16 = sq16; q3.y2t = y2t;
        qvk3_k<<<512, 256, 0, stream>>>(q3);

        AP2 ap{};
        ap.A16 = d16; ap.B0 = y2t; ap.sq = sq16; ap.gh = gh; ap.gl = gl;
        ap.s1 = log_scale; ap.s2 = aft_alpha; ap.s2i = l;
        aft2_k<1, 1><<<512, 256, 0, stream>>>(ap);

        inorm_k<1><<<dim3(B_, 8), 256, 0, stream>>>(
            xh, xl, gh, gl, nullptr, n1_w + l * 128, n1_b + l * 128, hh, hl);

        F12 f12{};
        f12.A0 = hh; f12.A1 = hl;
        f12.w1h = w1t_h + l * 65536; f12.w1l = w1t_l + l * 65536;
        f12.w2h = w2t_h + l * 65536; f12.w2l = w2t_l + l * 65536;
        f12.b1 = ffb1 + l * 512; f12.b2 = ffb2 + l * 128;
        f12.of = ff2;
        ffn12_k<<<512, 512, 0, stream>>>(f12);

        inorm_k<2><<<dim3(B_, 8), 256, 0, stream>>>(
            hh, hl, nullptr, nullptr, ff2, n2_w + l * 128, n2_b + l * 128, xh, xl);
    }

    // ---- decoder ---- (enc = xh/xl)
    {
        QV qv{};
        qv.A0 = xh; qv.A1 = xl;
        qv.vh = dvt_h; qv.vl = dvt_l;
        qv.kh = dkt_h; qv.kl = dkt_l;
        qv.y2t = y2t;
        qvk_vk_k<<<512, 256, 0, stream>>>(qv);
        gq_k<<<B_, 512, 0, stream>>>(xh, xl, dWq, gq);

        decprep_k<<<8192, 256, 0, stream>>>(cur_dist, ninf, log_scale, dec_alpha, am16);

        AP2 ap{};
        ap.A16 = am16; ap.B0 = y2t; ap.gh = gh; ap.gl = gl;
        ap.s1 = log_scale; ap.s2 = dec_alpha; ap.s2i = 0;
        aft2_k<3, 0><<<512, 256, 0, stream>>>(ap);

        dec_aft_k<<<16384, 256, 0, stream>>>(gq, capacity, dWq, gh, gl, hh, hl);

        SP2 sp{};
        sp.A0 = hh; sp.A1 = hl; sp.B0 = xh; sp.B1 = xl;
        sp.out = out; sp.cd = cur_dist; sp.cm = ninf;
        sp.s1 = log_scale; sp.s2 = p_alpha;
        score_sm_k<<<512, 512, 0, stream>>>(sp);
    }
}

// Round 5
// 1055.226 us; speedup vs baseline: 1.1353x; 1.0723x over previous
//
#include <hip/hip_runtime.h>
#include <math.h>

#define B_ 64
#define N_ 512
#define P_ 512
#define E_ 128
#define F_ 512
#define L_ 6
#define SQRT_E_INV 0.08838834764831843f

typedef unsigned short u16;
typedef __attribute__((ext_vector_type(8))) short bf8;
typedef __attribute__((ext_vector_type(16))) float f16v;

__device__ inline u16 bf16r(float f) {
    unsigned u = __float_as_uint(f);
    u += 0x7fffu + ((u >> 16) & 1u);
    return (u16)(u >> 16);
}
__device__ inline float bf2f(u16 h) { return __uint_as_float((unsigned)h << 16); }

#define MFMA(a, b, c) __builtin_amdgcn_mfma_f32_32x32x16_bf16(a, b, c, 0, 0, 0)

// ===========================================================================
// qvk3_k: fused q/v/k for encoder layers. Tile 64 rows x 128 cols, K=128.
// ===========================================================================
struct Q3 {
    const u16 *A0, *A1;
    const u16 *qh, *ql, *vh, *vl, *kh, *kl;
    u16 *sq16, *y2t;
};

__launch_bounds__(256, 2) __global__ void qvk3_k(Q3 p)
{
    const int tid = threadIdx.x;
    const int lane = tid & 63, wv = tid >> 6;
    const int wm = wv & 1, wn = wv >> 1;
    const int ln = lane & 31, hk = lane >> 5;
    const int row0 = blockIdx.x * 64;

    __shared__ __align__(16) u16 As[2][64][40];
    __shared__ __align__(16) u16 Bs[6][128][40];

    f16v aq[2], av[2], ak[2];
#pragma unroll
    for (int nt = 0; nt < 2; ++nt)
#pragma unroll
        for (int q = 0; q < 16; ++q) { aq[nt][q] = 0.f; av[nt][q] = 0.f; ak[nt][q] = 0.f; }

    const int r = tid >> 2, kq = tid & 3;
    for (int k0 = 0; k0 < 128; k0 += 32) {
        size_t ga = (size_t)(row0 + r) * 128 + k0 + kq * 8;
        *(uint4*)&As[0][r][kq * 8] = *(const uint4*)(p.A0 + ga);
        *(uint4*)&As[1][r][kq * 8] = *(const uint4*)(p.A1 + ga);
#pragma unroll
        for (int i = 0; i < 2; ++i) {
            int s = tid + i * 256;
            int rb2 = s >> 2, q = s & 3;
            size_t gb = (size_t)rb2 * 128 + k0 + q * 8;
            *(uint4*)&Bs[0][rb2][q * 8] = *(const uint4*)(p.qh + gb);
            *(uint4*)&Bs[1][rb2][q * 8] = *(const uint4*)(p.ql + gb);
            *(uint4*)&Bs[2][rb2][q * 8] = *(const uint4*)(p.vh + gb);
            *(uint4*)&Bs[3][rb2][q * 8] = *(const uint4*)(p.vl + gb);
            *(uint4*)&Bs[4][rb2][q * 8] = *(const uint4*)(p.kh + gb);
            *(uint4*)&Bs[5][rb2][q * 8] = *(const uint4*)(p.kl + gb);
        }
        __syncthreads();
#pragma unroll
        for (int s = 0; s < 2; ++s) {
            bf8 ah = *(const bf8*)&As[0][wm * 32 + ln][s * 16 + hk * 8];
            bf8 al = *(const bf8*)&As[1][wm * 32 + ln][s * 16 + hk * 8];
#pragma unroll
            for (int nt = 0; nt < 2; ++nt) {
                const int br = wn * 64 + nt * 32 + ln, sc = s * 16 + hk * 8;
                bf8 bqh = *(const bf8*)&Bs[0][br][sc];
                bf8 bql = *(const bf8*)&Bs[1][br][sc];
                bf8 bvh = *(const bf8*)&Bs[2][br][sc];
                bf8 bvl = *(const bf8*)&Bs[3][br][sc];
                bf8 bkh = *(const bf8*)&Bs[4][br][sc];
                bf8 bkl = *(const bf8*)&Bs[5][br][sc];
                aq[nt] = MFMA(ah, bqh, aq[nt]);
                aq[nt] = MFMA(ah, bql, aq[nt]);
                aq[nt] = MFMA(al, bqh, aq[nt]);
                av[nt] = MFMA(ah, bvh, av[nt]);
                av[nt] = MFMA(ah, bvl, av[nt]);
                av[nt] = MFMA(al, bvh, av[nt]);
                ak[nt] = MFMA(ah, bkh, ak[nt]);
                ak[nt] = MFMA(ah, bkl, ak[nt]);
                ak[nt] = MFMA(al, bkh, ak[nt]);
            }
        }
        __syncthreads();
    }

#pragma unroll
    for (int nt = 0; nt < 2; ++nt) {
        int gn = wn * 64 + nt * 32 + ln;
#pragma unroll
        for (int g = 0; g < 4; ++g) {
            int rb = row0 + wm * 32 + g * 8 + hk * 4;
            int bb = rb >> 9, nb = rb & 511;
            u16 pe[4], pv[4];
#pragma unroll
            for (int rr = 0; rr < 4; ++rr) {
                float vq = aq[nt][g * 4 + rr];
                p.sq16[(size_t)(rb + rr) * 128 + gn] =
                    bf16r(1.f / (1.f + __expf(-vq)));
                u16 hv = bf16r(av[nt][g * 4 + rr]);
                u16 he = bf16r(__expf(ak[nt][g * 4 + rr]));
                pe[rr] = he;
                pv[rr] = bf16r(bf2f(hv) * bf2f(he));
            }
            uint2 ue, uv;
            ue.x = pe[0] | ((unsigned)pe[1] << 16);
            ue.y = pe[2] | ((unsigned)pe[3] << 16);
            uv.x = pv[0] | ((unsigned)pv[1] << 16);
            uv.y = pv[2] | ((unsigned)pv[3] << 16);
            *(uint2*)(p.y2t + (size_t)bb * 131072 + (size_t)gn * 512 + nb) = uv;
            *(uint2*)(p.y2t + (size_t)bb * 131072 + (size_t)(128 + gn) * 512 + nb) = ue;
        }
    }
}

// ===========================================================================
// qvk_vk_k: decoder v/k (no q).
// ===========================================================================
struct QV {
    const u16 *A0, *A1;
    const u16 *vh, *vl, *kh, *kl;
    u16* y2t;
};

__launch_bounds__(256, 3) __global__ void qvk_vk_k(QV p)
{
    const int tid = threadIdx.x;
    const int lane = tid & 63, wv = tid >> 6;
    const int wm = wv & 1, wn = wv >> 1;
    const int ln = lane & 31, hk = lane >> 5;
    const int row0 = blockIdx.x * 64;

    __shared__ __align__(16) u16 As[2][64][40];
    __shared__ __align__(16) u16 Bs[4][128][40];

    f16v av[2], ak[2];
#pragma unroll
    for (int nt = 0; nt < 2; ++nt)
#pragma unroll
        for (int q = 0; q < 16; ++q) { av[nt][q] = 0.f; ak[nt][q] = 0.f; }

    const int r = tid >> 2, kq = tid & 3;
    for (int k0 = 0; k0 < 128; k0 += 32) {
        size_t ga = (size_t)(row0 + r) * 128 + k0 + kq * 8;
        *(uint4*)&As[0][r][kq * 8] = *(const uint4*)(p.A0 + ga);
        *(uint4*)&As[1][r][kq * 8] = *(const uint4*)(p.A1 + ga);
#pragma unroll
        for (int i = 0; i < 2; ++i) {
            int s = tid + i * 256;
            int rb2 = s >> 2, q = s & 3;
            size_t gb = (size_t)rb2 * 128 + k0 + q * 8;
            *(uint4*)&Bs[0][rb2][q * 8] = *(const uint4*)(p.vh + gb);
            *(uint4*)&Bs[1][rb2][q * 8] = *(const uint4*)(p.vl + gb);
            *(uint4*)&Bs[2][rb2][q * 8] = *(const uint4*)(p.kh + gb);
            *(uint4*)&Bs[3][rb2][q * 8] = *(const uint4*)(p.kl + gb);
        }
        __syncthreads();
#pragma unroll
        for (int s = 0; s < 2; ++s) {
            bf8 ah = *(const bf8*)&As[0][wm * 32 + ln][s * 16 + hk * 8];
            bf8 al = *(const bf8*)&As[1][wm * 32 + ln][s * 16 + hk * 8];
#pragma unroll
            for (int nt = 0; nt < 2; ++nt) {
                const int br = wn * 64 + nt * 32 + ln, sc = s * 16 + hk * 8;
                bf8 bvh = *(const bf8*)&Bs[0][br][sc];
                bf8 bvl = *(const bf8*)&Bs[1][br][sc];
                bf8 bkh = *(const bf8*)&Bs[2][br][sc];
                bf8 bkl = *(const bf8*)&Bs[3][br][sc];
                av[nt] = MFMA(ah, bvh, av[nt]);
                av[nt] = MFMA(ah, bvl, av[nt]);
                av[nt] = MFMA(al, bvh, av[nt]);
                ak[nt] = MFMA(ah, bkh, ak[nt]);
                ak[nt] = MFMA(ah, bkl, ak[nt]);
                ak[nt] = MFMA(al, bkh, ak[nt]);
            }
        }
        __syncthreads();
    }

#pragma unroll
    for (int nt = 0; nt < 2; ++nt) {
        int gn = wn * 64 + nt * 32 + ln;
#pragma unroll
        for (int g = 0; g < 4; ++g) {
            int rb = row0 + wm * 32 + g * 8 + hk * 4;
            int bb = rb >> 9, nb = rb & 511;
            u16 pe[4], pv[4];
#pragma unroll
            for (int rr = 0; rr < 4; ++rr) {
                u16 hv = bf16r(av[nt][g * 4 + rr]);
                u16 he = bf16r(__expf(ak[nt][g * 4 + rr]));
                pe[rr] = he;
                pv[rr] = bf16r(bf2f(hv) * bf2f(he));
            }
            uint2 ue, uv;
            ue.x = pe[0] | ((unsigned)pe[1] << 16);
            ue.y = pe[2] | ((unsigned)pe[3] << 16);
            uv.x = pv[0] | ((unsigned)pv[1] << 16);
            uv.y = pv[2] | ((unsigned)pv[3] << 16);
            *(uint2*)(p.y2t + (size_t)bb * 131072 + (size_t)gn * 512 + nb) = uv;
            *(uint2*)(p.y2t + (size_t)bb * 131072 + (size_t)(128 + gn) * 512 + nb) = ue;
        }
    }
}

// ===========================================================================
// aft2_k: AFT aggregation, num+den in one block. A-plane is bf16:
// OPA1: A = exp(ascale * a16)   (encoder, a16 = bf16(dist))
// OPA3: A = exp(a16)            (decoder, a16 = bf16(as*cd + ninf) prefused)
// SG1: multiply staged sigmoid plane (encoder); SG2: decoder fusion —
// multiply sigmoid(gq + cap*dWq_last) computed inline (kills dec_aft_k).
// ===========================================================================
struct AP2 {
    const u16 *A16;
    const u16 *B0, *sq;
    u16 *gh, *gl;
    const float *s1, *s2; int s2i;
    const float *gq, *cap, *dWq;
};

template <int OPA, int SG>
__launch_bounds__(256, 3) __global__ void aft2_k(AP2 p)
{
    const int tid = threadIdx.x;
    const int lane = tid & 63, wv = tid >> 6;
    const int wm = wv & 1, wn = wv >> 1;
    const int ln = lane & 31, hk = lane >> 5;

    const int id = blockIdx.x;
    const int xcd = id & 7, slot = id >> 3;
    const int bz = xcd * 8 + (slot >> 3);
    const int row0 = (slot & 7) * 64;

    __shared__ __align__(16) u16 As[2][64][40];
    __shared__ __align__(16) u16 Bs[2][256][40];

    f16v acc[4];
#pragma unroll
    for (int j = 0; j < 4; ++j)
#pragma unroll
        for (int q = 0; q < 16; ++q) acc[j][q] = 0.f;

    const float ascale = (OPA == 1) ? p.s1[0] * p.s2[p.s2i] : 0.f;
    const u16* Af = p.A16 + (size_t)bz * 262144 + (size_t)row0 * 512;
    const u16* Bb = p.B0 + (size_t)bz * 131072;

    const int r = tid >> 2, kq = tid & 3;
    uint4 va;
    uint4 vb[4];

#define AFT_LOAD(K0)                                                          \
    {                                                                         \
        va = *(const uint4*)(Af + (size_t)r * 512 + (K0) + kq * 8);           \
        size_t gb = (size_t)tid * 512 + (K0);                                 \
        _Pragma("unroll") for (int q = 0; q < 4; ++q)                         \
            vb[q] = *(const uint4*)(Bb + gb + q * 8);                         \
    }

#define AFT_WRITE(BUF)                                                        \
    {                                                                         \
        u16 a8[8];                                                            \
        *(uint4*)a8 = va;                                                     \
        float f[8];                                                           \
        _Pragma("unroll") for (int j = 0; j < 8; ++j) {                       \
            float t = bf2f(a8[j]);                                            \
            if (OPA == 1) t *= ascale;                                        \
            f[j] = __expf(t);                                                 \
        }                                                                     \
        uint4 pk;                                                             \
        pk.x = bf16r(f[0]) | ((unsigned)bf16r(f[1]) << 16);                   \
        pk.y = bf16r(f[2]) | ((unsigned)bf16r(f[3]) << 16);                   \
        pk.z = bf16r(f[4]) | ((unsigned)bf16r(f[5]) << 16);                   \
        pk.w = bf16r(f[6]) | ((unsigned)bf16r(f[7]) << 16);                   \
        *(uint4*)&As[BUF][r][kq * 8] = pk;                                    \
        _Pragma("unroll") for (int q = 0; q < 4; ++q)                         \
            *(uint4*)&Bs[BUF][tid][q * 8] = vb[q];                            \
    }

#define AFT_COMPUTE(BUF)                                                      \
    {                                                                         \
        _Pragma("unroll") for (int s = 0; s < 2; ++s) {                       \
            bf8 ah = *(const bf8*)&As[BUF][wm * 32 + ln][s * 16 + hk * 8];    \
            _Pragma("unroll") for (int j = 0; j < 4; ++j) {                   \
                int br = ((j >> 1) << 7) + wn * 64 + ((j & 1) << 5) + ln;     \
                bf8 bh = *(const bf8*)&Bs[BUF][br][s * 16 + hk * 8];          \
                acc[j] = MFMA(ah, bh, acc[j]);                                \
            }                                                                 \
        }                                                                     \
    }

    AFT_LOAD(0);
    AFT_WRITE(0);
    __syncthreads();

    int cur = 0;
    for (int k0 = 32; k0 < 512; k0 += 32) {
        AFT_LOAD(k0);
        AFT_COMPUTE(cur);
        AFT_WRITE(cur ^ 1);
        __syncthreads();
        cur ^= 1;
    }
    AFT_COMPUTE(cur);

#undef AFT_LOAD
#undef AFT_WRITE
#undef AFT_COMPUTE

    const u16* sqb = (SG == 1) ? (p.sq + (size_t)bz * 65536) : (const u16*)0;
    u16* ghb = p.gh + (size_t)bz * 65536;
    u16* glb = p.gl + (size_t)bz * 65536;
#pragma unroll
    for (int j = 0; j < 2; ++j) {
        int e = wn * 64 + j * 32 + ln;
#pragma unroll
        for (int g = 0; g < 4; ++g) {
#pragma unroll
            for (int rr = 0; rr < 4; ++rr) {
                int row = row0 + wm * 32 + g * 8 + hk * 4 + rr;
                float num = acc[j][g * 4 + rr];
                float den = acc[j + 2][g * 4 + rr];
                float pv = num / den;
                if (SG == 1) pv *= bf2f(sqb[(size_t)row * 128 + e]);
                if (SG == 2) {
                    float qv = fmaf(p.cap[(size_t)bz * 512 + row],
                                    p.dWq[128 * 128 + e], p.gq[bz * 128 + e]);
                    pv *= 1.f / (1.f + __expf(-qv));
                }
                u16 hi = bf16r(pv);
                ghb[(size_t)row * 128 + e] = hi;
                glb[(size_t)row * 128 + e] = bf16r(pv - bf2f(hi));
            }
        }
    }
}

// ===========================================================================
// ffn12_k v2: fused FFN, double-buffered reg-staged weight pipeline.
// ===========================================================================
struct F12 {
    const u16 *A0, *A1;
    const u16 *w1h, *w1l;      // [512][128]
    const u16 *w2h, *w2l;      // [128][512]
    const float *b1, *b2;
    float* of;
};

__launch_bounds__(512, 2) __global__ void ffn12_k(F12 p)
{
    const int tid = threadIdx.x;
    const int lane = tid & 63, wv = tid >> 6;
    const int wm = wv & 1, wn = wv >> 1;
    const int ln = lane & 31, hk = lane >> 5;
    const int row0 = blockIdx.x * 64;

    __shared__ __align__(16) u16 Ws[2][2][128][72];
    __shared__ __align__(16) u16 ff1c[4][64][136];

    bf8 ar0[8], ar1[8];
    {
        const size_t arow = (size_t)(row0 + wm * 32 + ln) * 128;
#pragma unroll
        for (int s = 0; s < 8; ++s) {
            ar0[s] = *(const bf8*)(p.A0 + arow + s * 16 + hk * 8);
            ar1[s] = *(const bf8*)(p.A1 + arow + s * 16 + hk * 8);
        }
    }

    const int lcol = wn * 32 + ln;
    const int sc_ = tid >> 3, sq_ = tid & 7;
    uint4 wr[2][2];

#define F_LOAD1(CT, KC)                                                       \
    {                                                                         \
        _Pragma("unroll") for (int pl = 0; pl < 2; ++pl) {                    \
            const u16* src = pl ? p.w1l : p.w1h;                              \
            _Pragma("unroll") for (int it = 0; it < 2; ++it) {                \
                int c = sc_ + it * 64;                                        \
                wr[pl][it] = *(const uint4*)(src +                            \
                    (size_t)((CT) * 128 + c) * 128 + (KC) * 64 + sq_ * 8);    \
            }                                                                 \
        }                                                                     \
    }

#define F_LOAD2(J)                                                            \
    {                                                                         \
        _Pragma("unroll") for (int pl = 0; pl < 2; ++pl) {                    \
            const u16* src = pl ? p.w2l : p.w2h;                              \
            _Pragma("unroll") for (int it = 0; it < 2; ++it) {                \
                int c = sc_ + it * 64;                                        \
                wr[pl][it] = *(const uint4*)(src +                            \
                    (size_t)c * 512 + (J) * 64 + sq_ * 8);                    \
            }                                                                 \
        }                                                                     \
    }

#define F_STORE(BUF)                                                          \
    {                                                                         \
        _Pragma("unroll") for (int pl = 0; pl < 2; ++pl)                      \
            _Pragma("unroll") for (int it = 0; it < 2; ++it)                  \
                *(uint4*)&Ws[BUF][pl][sc_ + it * 64][sq_ * 8] = wr[pl][it];   \
    }

    // ---- phase 1 ----
    F_LOAD1(0, 0);
    F_STORE(0);
    __syncthreads();
    int buf = 0;
    f16v a0, a1, a2;
#pragma unroll
    for (int st = 0; st < 8; ++st) {
        const int ct = st >> 1, kc = st & 1;
        if (st < 7) { F_LOAD1((st + 1) >> 1, (st + 1) & 1); }
        else        { F_LOAD2(0); }
        if (kc == 0) {
#pragma unroll
            for (int q = 0; q < 16; ++q) { a0[q] = 0.f; a1[q] = 0.f; a2[q] = 0.f; }
        }
#pragma unroll
        for (int s = 0; s < 4; ++s) {
            bf8 bh = *(const bf8*)&Ws[buf][0][lcol][s * 16 + hk * 8];
            bf8 bl = *(const bf8*)&Ws[buf][1][lcol][s * 16 + hk * 8];
            a0 = MFMA(ar0[kc * 4 + s], bh, a0);
            a1 = MFMA(ar0[kc * 4 + s], bl, a1);
            a2 = MFMA(ar1[kc * 4 + s], bh, a2);
        }
        if (kc == 1) {
            float bv = p.b1[ct * 128 + lcol];
#pragma unroll
            for (int g = 0; g < 4; ++g)
#pragma unroll
                for (int rr = 0; rr < 4; ++rr) {
                    int lr = wm * 32 + g * 8 + hk * 4 + rr;
                    float v = a0[g * 4 + rr] + a1[g * 4 + rr] + a2[g * 4 + rr] + bv;
                    ff1c[ct][lr][lcol] = bf16r(fmaxf(v, 0.f));
                }
        }
        F_STORE(buf ^ 1);
        __syncthreads();
        buf ^= 1;
    }

    // ---- phase 2 ----
    f16v c0, c1;
#pragma unroll
    for (int q = 0; q < 16; ++q) { c0[q] = 0.f; c1[q] = 0.f; }
#pragma unroll
    for (int j = 0; j < 8; ++j) {
        if (j < 7) F_LOAD2(j + 1);
#pragma unroll
        for (int s = 0; s < 4; ++s) {
            bf8 af = *(const bf8*)&ff1c[j >> 1][wm * 32 + ln]
                                      [(j & 1) * 64 + s * 16 + hk * 8];
            bf8 bh = *(const bf8*)&Ws[buf][0][lcol][s * 16 + hk * 8];
            bf8 bl = *(const bf8*)&Ws[buf][1][lcol][s * 16 + hk * 8];
            c0 = MFMA(af, bh, c0);
            c1 = MFMA(af, bl, c1);
        }
        if (j < 7) {
            F_STORE(buf ^ 1);
            __syncthreads();
            buf ^= 1;
        }
    }

#undef F_LOAD1
#undef F_LOAD2
#undef F_STORE

    float bv = p.b2[lcol];
#pragma unroll
    for (int g = 0; g < 4; ++g)
#pragma unroll
        for (int rr = 0; rr < 4; ++rr) {
            int rb = row0 + wm * 32 + g * 8 + hk * 4 + rr;
            p.of[(size_t)rb * 128 + lcol] = c0[g * 4 + rr] + c1[g * 4 + rr] + bv;
        }
}

// ===========================================================================
// score_sm_k v3: fused score+softmax, 1024 threads (16 waves, 2x8), 64 rows
// x 512 cols per block. Per-thread state accs[2] (32 VGPR) -> no spills.
// B staged as full-batch K-slices [2][512][32k]. 1 block/CU (116 KB LDS),
// 16 waves. cd/cm loaded inline per nt in the epilogue.
// ===========================================================================
struct SP2 {
    const u16 *A0, *A1, *B0, *B1;
    float* out;
    const float *cd, *cm;
    const float *s1, *s2;
};

__launch_bounds__(1024, 4) __global__ void score_sm_k(SP2 p)
{
    const int tid = threadIdx.x;
    const int lane = tid & 63, wv = tid >> 6;      // wv 0..15
    const int wm = wv & 1, wn = wv >> 1;            // wn 0..7
    const int ln = lane & 31, hk = lane >> 5;

    const int id = blockIdx.x;
    const int xcd = id & 7, s_ = id >> 3;
    const int bz = xcd * 8 + (s_ & 7);
    const int row0 = (s_ >> 3) * 64;

    __shared__ __align__(16) u16 As[2][64][136];
    __shared__ __align__(16) u16 Bs[2][512][40];
    __shared__ float rs[8][64];

    // stage A (aft rows) once: 2 planes x 64 rows x 128 cols
#pragma unroll
    for (int i = 0; i < 2; ++i) {
        int idx = tid + i * 1024;
        int pl = idx >> 10, rem = idx & 1023;
        int row = rem >> 4, q = rem & 15;
        const u16* src = pl ? p.A1 : p.A0;
        *(uint4*)&As[pl][row][q * 8] =
            *(const uint4*)(src + ((size_t)bz * 512 + row0 + row) * 128 + q * 8);
    }

    const float sp = p.s1[0] * p.s2[0];

    f16v accs[2];
#pragma unroll
    for (int nt = 0; nt < 2; ++nt)
#pragma unroll
        for (int q = 0; q < 16; ++q) accs[nt][q] = 0.f;

    for (int k0 = 0; k0 < 128; k0 += 32) {
#pragma unroll
        for (int i = 0; i < 4; ++i) {
            int idx = tid + i * 1024;
            int pl = idx >> 11, rem = idx & 2047;
            int row = rem >> 2, q = rem & 3;
            const u16* src = pl ? p.B1 : p.B0;
            *(uint4*)&Bs[pl][row][q * 8] =
                *(const uint4*)(src + ((size_t)bz * 512 + row) * 128 + k0 + q * 8);
        }
        __syncthreads();
#pragma unroll
        for (int s = 0; s < 2; ++s) {
            bf8 ah = *(const bf8*)&As[0][wm * 32 + ln][k0 + s * 16 + hk * 8];
            bf8 al = *(const bf8*)&As[1][wm * 32 + ln][k0 + s * 16 + hk * 8];
#pragma unroll
            for (int nt = 0; nt < 2; ++nt) {
                bf8 bh = *(const bf8*)&Bs[0][wn * 64 + nt * 32 + ln][s * 16 + hk * 8];
                bf8 bl = *(const bf8*)&Bs[1][wn * 64 + nt * 32 + ln][s * 16 + hk * 8];
                accs[nt] = MFMA(ah, bh, accs[nt]);
                accs[nt] = MFMA(ah, bl, accs[nt]);
                accs[nt] = MFMA(al, bh, accs[nt]);
            }
        }
        __syncthreads();
    }

    // epilogue: score -> exp (kept in accs); cd/cm loaded inline per nt
    float rsum[16];
#pragma unroll
    for (int nt = 0; nt < 2; ++nt) {
        const int gn = wn * 64 + nt * 32 + ln;
        float cdv[16], cmv[16];
#pragma unroll
        for (int g = 0; g < 4; ++g)
#pragma unroll
            for (int rr = 0; rr < 4; ++rr) {
                int grow = row0 + wm * 32 + g * 8 + hk * 4 + rr;
                size_t ix = (size_t)bz * 262144 + (size_t)grow * 512 + gn;
                cdv[g * 4 + rr] = p.cd[ix];
                cmv[g * 4 + rr] = p.cm[ix];
            }
#pragma unroll
        for (int i = 0; i < 16; ++i) {
            float sc = fmaf(accs[nt][i], SQRT_E_INV, sp * cdv[i]);
            float e2 = __expf(2.f * sc);
            float th = 1.f - 2.f / (e2 + 1.f);
            float ev = __expf(10.f * th + cmv[i]);
            accs[nt][i] = ev;
            if (nt == 0) rsum[i] = ev; else rsum[i] += ev;
        }
    }

    // reduce row sums: 32 ln-lanes, then across the 8 wn groups via LDS
#pragma unroll
    for (int i = 0; i < 16; ++i) {
#pragma unroll
        for (int o = 1; o < 32; o <<= 1) rsum[i] += __shfl_xor(rsum[i], o);
    }
    __syncthreads();
    if (ln == 0) {
#pragma unroll
        for (int i = 0; i < 16; ++i) {
            int lr = wm * 32 + (i >> 2) * 8 + hk * 4 + (i & 3);
            rs[wn][lr] = rsum[i];
        }
    }
    __syncthreads();
    float invr[16];
#pragma unroll
    for (int i = 0; i < 16; ++i) {
        int lr = wm * 32 + (i >> 2) * 8 + hk * 4 + (i & 3);
        float t = rs[0][lr] + rs[1][lr] + rs[2][lr] + rs[3][lr]
                + rs[4][lr] + rs[5][lr] + rs[6][lr] + rs[7][lr];
        invr[i] = 1.f / t;
    }

#pragma unroll
    for (int nt = 0; nt < 2; ++nt) {
        int gn = wn * 64 + nt * 32 + ln;
#pragma unroll
        for (int g = 0; g < 4; ++g)
#pragma unroll
            for (int rr = 0; rr < 4; ++rr) {
                int grow = row0 + wm * 32 + g * 8 + hk * 4 + rr;
                size_t ix = (size_t)bz * 262144 + (size_t)grow * 512 + gn;
                p.out[ix] = accs[nt][g * 4 + rr] * invr[g * 4 + rr];
            }
    }
}

// ===========================================================================
// InstanceNorm over nodes, residual fused.
// ===========================================================================
template <int MODE>
__launch_bounds__(256) __global__ void inorm_k(
    const u16* __restrict__ ah, const u16* __restrict__ al,
    const u16* __restrict__ g0, const u16* __restrict__ g1,
    const float* __restrict__ f1,
    const float* __restrict__ nw, const float* __restrict__ nbv,
    u16* __restrict__ oh, u16* __restrict__ ol)
{
    const int bb = blockIdx.x, e0 = blockIdx.y * 16;
    const int tid = threadIdx.x, el = tid & 3, no = tid >> 2;
    const size_t base = (size_t)bb * N_ * E_ + e0 + el * 4;

    float4 vals[8];
    float s1x = 0, s1y = 0, s1z = 0, s1w = 0;
    float s2x = 0, s2y = 0, s2z = 0, s2w = 0;
#pragma unroll
    for (int i = 0; i < 8; ++i) {
        int n = no * 8 + i;
        size_t ad = base + (size_t)n * E_;
        uint2 h2 = *(const uint2*)(ah + ad);
        uint2 l2 = *(const uint2*)(al + ad);
        float x0 = bf2f((u16)h2.x) + bf2f((u16)l2.x);
        float x1 = bf2f((u16)(h2.x >> 16)) + bf2f((u16)(l2.x >> 16));
        float x2 = bf2f((u16)h2.y) + bf2f((u16)l2.y);
        float x3 = bf2f((u16)(h2.y >> 16)) + bf2f((u16)(l2.y >> 16));
        float4 v;
        if (MODE == 1) {
            uint2 a2 = *(const uint2*)(g0 + ad);
            uint2 b2 = *(const uint2*)(g1 + ad);
            v.x = x0 + bf2f((u16)a2.x) + bf2f((u16)b2.x);
            v.y = x1 + bf2f((u16)(a2.x >> 16)) + bf2f((u16)(b2.x >> 16));
            v.z = x2 + bf2f((u16)a2.y) + bf2f((u16)b2.y);
            v.w = x3 + bf2f((u16)(a2.y >> 16)) + bf2f((u16)(b2.y >> 16));
        } else {
            float4 ff = *(const float4*)(f1 + ad);
            v.x = x0 + ff.x; v.y = x1 + ff.y; v.z = x2 + ff.z; v.w = x3 + ff.w;
        }
        vals[i] = v;
        s1x += v.x; s1y += v.y; s1z += v.z; s1w += v.w;
        s2x = fmaf(v.x, v.x, s2x); s2y = fmaf(v.y, v.y, s2y);
        s2z = fmaf(v.z, v.z, s2z); s2w = fmaf(v.w, v.w, s2w);
    }

    __shared__ float4 r1[256], r2[256];
    r1[tid] = make_float4(s1x, s1y, s1z, s1w);
    r2[tid] = make_float4(s2x, s2y, s2z, s2w);
    __syncthreads();
    for (int s = 128; s >= 4; s >>= 1) {
        if (tid < s) {
            float4 u = r1[tid], w = r1[tid + s];
            r1[tid] = make_float4(u.x + w.x, u.y + w.y, u.z + w.z, u.w + w.w);
            float4 pq = r2[tid], q = r2[tid + s];
            r2[tid] = make_float4(pq.x + q.x, pq.y + q.y, pq.z + q.z, pq.w + q.w);
        }
        __syncthreads();
    }
    __shared__ float4 mu_s[4], rs_s[4];
    if (tid < 4) {
        float4 m = r1[tid], q = r2[tid];
        m.x *= (1.f / N_); m.y *= (1.f / N_); m.z *= (1.f / N_); m.w *= (1.f / N_);
        q.x *= (1.f / N_); q.y *= (1.f / N_); q.z *= (1.f / N_); q.w *= (1.f / N_);
        float4 rsq;
        rsq.x = rsqrtf(q.x - m.x * m.x + 1e-5f);
        rsq.y = rsqrtf(q.y - m.y * m.y + 1e-5f);
        rsq.z = rsqrtf(q.z - m.z * m.z + 1e-5f);
        rsq.w = rsqrtf(q.w - m.w * m.w + 1e-5f);
        mu_s[tid] = m; rs_s[tid] = rsq;
    }
    __syncthreads();
    float4 mu = mu_s[el], rsq = rs_s[el];
    float4 w4 = *(const float4*)(nw + e0 + el * 4);
    float4 b4 = *(const float4*)(nbv + e0 + el * 4);
#pragma unroll
    for (int i = 0; i < 8; ++i) {
        size_t ad = base + (size_t)(no * 8 + i) * E_;
        float4 v = vals[i];
        v.x = fmaf((v.x - mu.x) * rsq.x, w4.x, b4.x);
        v.y = fmaf((v.y - mu.y) * rsq.y, w4.y, b4.y);
        v.z = fmaf((v.z - mu.z) * rsq.z, w4.z, b4.z);
        v.w = fmaf((v.w - mu.w) * rsq.w, w4.w, b4.w);
        u16 h0 = bf16r(v.x), h1 = bf16r(v.y), h2v = bf16r(v.z), h3 = bf16r(v.w);
        u16 l0 = bf16r(v.x - bf2f(h0)), l1 = bf16r(v.y - bf2f(h1));
        u16 l2v = bf16r(v.z - bf2f(h2v)), l3 = bf16r(v.w - bf2f(h3));
        uint2 ph, pl;
        ph.x = h0 | ((unsigned)h1 << 16); ph.y = h2v | ((unsigned)h3 << 16);
        pl.x = l0 | ((unsigned)l1 << 16); pl.y = l2v | ((unsigned)l3 << 16);
        *(uint2*)(oh + ad) = ph;
        *(uint2*)(ol + ad) = pl;
    }
}

// ===========================================================================
__global__ void wprep_k(const float* __restrict__ W, u16* __restrict__ Th,
                        u16* __restrict__ Tl, int K, int N)
{
    const int z = blockIdx.z;
    const float* Wz = W + (size_t)z * K * N;
    u16* Hh = Th + (size_t)z * K * N;
    u16* Hl = Tl + (size_t)z * K * N;
    __shared__ float t[32][33];
    const int j = threadIdx.x & 31, i0 = threadIdx.x >> 5;
    const int k0 = blockIdx.x * 32, n0 = blockIdx.y * 32;
    for (int i = i0; i < 32; i += 8)
        t[i][j] = Wz[(size_t)(k0 + i) * N + n0 + j];
    __syncthreads();
    for (int i = i0; i < 32; i += 8) {
        float v = t[j][i];
        u16 h = bf16r(v);
        u16 l = bf16r(v - bf2f(h));
        size_t o = (size_t)(n0 + i) * K + k0 + j;
        Hh[o] = h; Hl[o] = l;
    }
}

// distprep_k: d16 = bf16(dist)   (8 elems/thread)
__global__ void distprep_k(const float* __restrict__ src, u16* __restrict__ dst)
{
    size_t i = ((size_t)blockIdx.x * 256 + threadIdx.x) * 8;
    float4 f0 = *(const float4*)(src + i);
    float4 f1 = *(const float4*)(src + i + 4);
    uint4 pk;
    pk.x = bf16r(f0.x) | ((unsigned)bf16r(f0.y) << 16);
    pk.y = bf16r(f0.z) | ((unsigned)bf16r(f0.w) << 16);
    pk.z = bf16r(f1.x) | ((unsigned)bf16r(f1.y) << 16);
    pk.w = bf16r(f1.z) | ((unsigned)bf16r(f1.w) << 16);
    *(uint4*)(dst + i) = pk;
}

// decprep_k: am16 = bf16(da*cd + ninf)
__global__ void decprep_k(const float* __restrict__ cd, const float* __restrict__ nf,
                          const float* __restrict__ s1, const float* __restrict__ s2,
                          u16* __restrict__ dst)
{
    const float da = s1[0] * s2[0];
    size_t i = ((size_t)blockIdx.x * 256 + threadIdx.x) * 8;
    float4 c0 = *(const float4*)(cd + i);
    float4 c1 = *(const float4*)(cd + i + 4);
    float4 m0 = *(const float4*)(nf + i);
    float4 m1 = *(const float4*)(nf + i + 4);
    uint4 pk;
    pk.x = bf16r(fmaf(da, c0.x, m0.x)) | ((unsigned)bf16r(fmaf(da, c0.y, m0.y)) << 16);
    pk.y = bf16r(fmaf(da, c0.z, m0.z)) | ((unsigned)bf16r(fmaf(da, c0.w, m0.w)) << 16);
    pk.z = bf16r(fmaf(da, c1.x, m1.x)) | ((unsigned)bf16r(fmaf(da, c1.y, m1.y)) << 16);
    pk.w = bf16r(fmaf(da, c1.z, m1.z)) | ((unsigned)bf16r(fmaf(da, c1.w, m1.w)) << 16);
    *(uint4*)(dst + i) = pk;
}

__global__ void embed_k(const float* __restrict__ data, const float* __restrict__ W,
                        const float* __restrict__ bias,
                        u16* __restrict__ xh, u16* __restrict__ xl)
{
    size_t idx = (size_t)blockIdx.x * 256 + threadIdx.x;
    int e = idx & 127;
    size_t bn = idx >> 7;
    float v = fmaf(data[bn * 2], W[e], fmaf(data[bn * 2 + 1], W[128 + e], bias[e]));
    u16 h = bf16r(v);
    xh[idx] = h;
    xl[idx] = bf16r(v - bf2f(h));
}

__launch_bounds__(512) __global__
void gq_k(const u16* __restrict__ xh, const u16* __restrict__ xl,
          const float* __restrict__ dWq, float* __restrict__ gq)
{
    int b = blockIdx.x;
    int tid = threadIdx.x;
    int e = tid & 127, qd = tid >> 7;
    float s = 0.f;
    for (int n = qd; n < N_; n += 4) {
        size_t ix = ((size_t)b * N_ + n) * E_ + e;
        s += bf2f(xh[ix]) + bf2f(xl[ix]);
    }
    __shared__ float part[512];
    __shared__ float gm[128];
    part[tid] = s;
    __syncthreads();
    if (tid < 128)
        gm[tid] = (part[tid] + part[tid + 128] + part[tid + 256] + part[tid + 384]) *
                  (1.f / N_);
    __syncthreads();
    if (tid < 128) {
        float acc = 0.f;
        for (int kk = 0; kk < 128; ++kk) acc = fmaf(gm[kk], dWq[kk * 128 + tid], acc);
        gq[b * 128 + tid] = acc;
    }
}

// ===========================================================================
extern "C" void kernel_launch(void* const* d_in, const int* in_sizes, int n_in,
                              void* d_out, int out_size, void* d_ws, size_t ws_size,
                              hipStream_t stream)
{
    const float* data      = (const float*)d_in[0];
    const float* dist      = (const float*)d_in[1];
    const float* cur_dist  = (const float*)d_in[2];
    const float* capacity  = (const float*)d_in[3];
    const float* ninf      = (const float*)d_in[4];
    const float* log_scale = (const float*)d_in[5];
    const float* emb_W     = (const float*)d_in[6];
    const float* emb_b     = (const float*)d_in[7];
    const float* Wq        = (const float*)d_in[8];
    const float* Wk        = (const float*)d_in[9];
    const float* Wv        = (const float*)d_in[10];
    const float* aft_alpha = (const float*)d_in[11];
    const float* n1_w      = (const float*)d_in[12];
    const float* n1_b      = (const float*)d_in[13];
    const float* ffW1      = (const float*)d_in[14];
    const float* ffb1      = (const float*)d_in[15];
    const float* ffW2      = (const float*)d_in[16];
    const float* ffb2      = (const float*)d_in[17];
    const float* n2_w      = (const float*)d_in[18];
    const float* n2_b      = (const float*)d_in[19];
    const float* dWq       = (const float*)d_in[20];
    const float* dWk       = (const float*)d_in[21];
    const float* dWv       = (const float*)d_in[22];
    const float* dec_alpha = (const float*)d_in[23];
    const float* p_alpha   = (const float*)d_in[24];
    float* out = (float*)d_out;

    char* W = (char*)d_ws;
    size_t off = 0;
    auto take = [&](size_t n) { void* pp = W + off; off += (n + 255) & ~(size_t)255; return pp; };
    const size_t SZP = (size_t)B_ * N_ * E_ * 2;   // 8 MB bf16 plane

    u16* xh   = (u16*)take(SZP);
    u16* xl   = (u16*)take(SZP);
    u16* hh   = (u16*)take(SZP);
    u16* hl   = (u16*)take(SZP);
    u16* sq16 = (u16*)take(SZP);
    u16* gh   = (u16*)take(SZP);
    u16* gl   = (u16*)take(SZP);
    u16* y2t  = (u16*)take(2 * SZP);
    float* ff2 = (float*)take((size_t)B_ * N_ * E_ * 4);   // 16 MB fp32
    u16* d16  = (u16*)take((size_t)B_ * N_ * N_ * 2);      // 32 MB bf16 dist
    u16* wqt_h = (u16*)take(196608); u16* wqt_l = (u16*)take(196608);
    u16* wkt_h = (u16*)take(196608); u16* wkt_l = (u16*)take(196608);
    u16* wvt_h = (u16*)take(196608); u16* wvt_l = (u16*)take(196608);
    u16* w1t_h = (u16*)take(786432); u16* w1t_l = (u16*)take(786432);
    u16* w2t_h = (u16*)take(786432); u16* w2t_l = (u16*)take(786432);
    u16* dkt_h = (u16*)take(32768);  u16* dkt_l = (u16*)take(32768);
    u16* dvt_h = (u16*)take(32768);  u16* dvt_l = (u16*)take(32768);
    float* gq = (float*)take(32768);
    if (ws_size < off) return;

    u16* am16 = d16;   // decoder A-plane aliases d16 (dead after encoder)

    // ---- weight prep ----
    wprep_k<<<dim3(4, 4, 6), 256, 0, stream>>>(Wq, wqt_h, wqt_l, 128, 128);
    wprep_k<<<dim3(4, 4, 6), 256, 0, stream>>>(Wk, wkt_h, wkt_l, 128, 128);
    wprep_k<<<dim3(4, 4, 6), 256, 0, stream>>>(Wv, wvt_h, wvt_l, 128, 128);
    wprep_k<<<dim3(4, 16, 6), 256, 0, stream>>>(ffW1, w1t_h, w1t_l, 128, 512);
    wprep_k<<<dim3(16, 4, 6), 256, 0, stream>>>(ffW2, w2t_h, w2t_l, 512, 128);
    wprep_k<<<dim3(4, 4, 1), 256, 0, stream>>>(dWk, dkt_h, dkt_l, 128, 128);
    wprep_k<<<dim3(4, 4, 1), 256, 0, stream>>>(dWv, dvt_h, dvt_l, 128, 128);

    distprep_k<<<8192, 256, 0, stream>>>(dist, d16);
    embed_k<<<16384, 256, 0, stream>>>(data, emb_W, emb_b, xh, xl);

    for (int l = 0; l < L_; ++l) {
        Q3 q3{};
        q3.A0 = xh; q3.A1 = xl;
        q3.qh = wqt_h + l * 16384; q3.ql = wqt_l + l * 16384;
        q3.vh = wvt_h + l * 16384; q3.vl = wvt_l + l * 16384;
        q3.kh = wkt_h + l * 16384; q3.kl = wkt_l + l * 16384;
        q3.sq16 = sq16; q3.y2t = y2t;
        qvk3_k<<<512, 256, 0, stream>>>(q3);

        AP2 ap{};
        ap.A16 = d16; ap.B0 = y2t; ap.sq = sq16; ap.gh = gh; ap.gl = gl;
        ap.s1 = log_scale; ap.s2 = aft_alpha; ap.s2i = l;
        aft2_k<1, 1><<<512, 256, 0, stream>>>(ap);

        inorm_k<1><<<dim3(B_, 8), 256, 0, stream>>>(
            xh, xl, gh, gl, nullptr, n1_w + l * 128, n1_b + l * 128, hh, hl);

        F12 f12{};
        f12.A0 = hh; f12.A1 = hl;
        f12.w1h = w1t_h + l * 65536; f12.w1l = w1t_l + l * 65536;
        f12.w2h = w2t_h + l * 65536; f12.w2l = w2t_l + l * 65536;
        f12.b1 = ffb1 + l * 512; f12.b2 = ffb2 + l * 128;
        f12.of = ff2;
        ffn12_k<<<512, 512, 0, stream>>>(f12);

        inorm_k<2><<<dim3(B_, 8), 256, 0, stream>>>(
            hh, hl, nullptr, nullptr, ff2, n2_w + l * 128, n2_b + l * 128, xh, xl);
    }

    // ---- decoder ---- (enc = xh/xl)
    {
        QV qv{};
        qv.A0 = xh; qv.A1 = xl;
        qv.vh = dvt_h; qv.vl = dvt_l;
        qv.kh = dkt_h; qv.kl = dkt_l;
        qv.y2t = y2t;
        qvk_vk_k<<<512, 256, 0, stream>>>(qv);
        gq_k<<<B_, 512, 0, stream>>>(xh, xl, dWq, gq);

        decprep_k<<<8192, 256, 0, stream>>>(cur_dist, ninf, log_scale, dec_alpha, am16);

        AP2 ap{};
        ap.A16 = am16; ap.B0 = y2t; ap.gh = hh; ap.gl = hl;
        ap.s1 = log_scale; ap.s2 = dec_alpha; ap.s2i = 0;
        ap.gq = gq; ap.cap = capacity; ap.dWq = dWq;
        aft2_k<3, 2><<<512, 256, 0, stream>>>(ap);

        SP2 sp{};
        sp.A0 = hh; sp.A1 = hl; sp.B0 = xh; sp.B1 = xl;
        sp.out = out; sp.cd = cur_dist; sp.cm = ninf;
        sp.s1 = log_scale; sp.s2 = p_alpha;
        score_sm_k<<<512, 1024, 0, stream>>>(sp);
    }
}

// Round 6
// 989.163 us; speedup vs baseline: 1.2111x; 1.0668x over previous
//
#include <hip/hip_runtime.h>
#include <math.h>

#define B_ 64
#define N_ 512
#define P_ 512
#define E_ 128
#define F_ 512
#define L_ 6
#define SQRT_E_INV 0.08838834764831843f

typedef unsigned short u16;
typedef __attribute__((ext_vector_type(8))) short bf8;
typedef __attribute__((ext_vector_type(16))) float f16v;

__device__ inline u16 bf16r(float f) {
    unsigned u = __float_as_uint(f);
    u += 0x7fffu + ((u >> 16) & 1u);
    return (u16)(u >> 16);
}
__device__ inline float bf2f(u16 h) { return __uint_as_float((unsigned)h << 16); }

#define MFMA(a, b, c) __builtin_amdgcn_mfma_f32_32x32x16_bf16(a, b, c, 0, 0, 0)

// Reduce pstats[b][8][e][2] -> muw[e] = rs*w[e], bb[e] = b[e] - mu*rs*w[e]
// so x = fma(val, muw[e], bb[e]). Caller must __syncthreads() after.
__device__ inline void norm_coef(const float* ps, const float* w, const float* b,
                                 int bz, int tid, float* muw, float* bb)
{
    if (tid < 128) {
        const float* base = ps + (size_t)bz * 2048 + tid * 2;
        float s = 0.f, q = 0.f;
#pragma unroll
        for (int k = 0; k < 8; ++k) { s += base[k * 256]; q += base[k * 256 + 1]; }
        float mu = s * (1.f / 512.f);
        float rs = rsqrtf(q * (1.f / 512.f) - mu * mu + 1e-5f);
        float mw = rs * w[tid];
        muw[tid] = mw;
        bb[tid] = b[tid] - mu * mw;
    }
}

// ===========================================================================
// qvk3_k: fused q/v/k for encoder layers. Tile 64 rows x 128 cols, K=128.
// NORM=1: A-source is (val2 hi/lo + pstats2 + n2 params) of prev layer,
// normalized on load. NORM=0: raw hi/lo planes (layer 0 = embed output).
// ===========================================================================
struct Q3 {
    const u16 *A0, *A1;
    const float *ps2, *pw, *pb;
    const u16 *qh, *ql, *vh, *vl, *kh, *kl;
    u16 *sq16, *y2t;
};

template <int NORM>
__launch_bounds__(256, 2) __global__ void qvk3_k(Q3 p)
{
    const int tid = threadIdx.x;
    const int lane = tid & 63, wv = tid >> 6;
    const int wm = wv & 1, wn = wv >> 1;
    const int ln = lane & 31, hk = lane >> 5;
    const int row0 = blockIdx.x * 64;

    __shared__ __align__(16) u16 As[2][64][40];
    __shared__ __align__(16) u16 Bs[6][128][40];
    __shared__ float muw[128], bbv[128];

    if (NORM) norm_coef(p.ps2, p.pw, p.pb, blockIdx.x >> 3, tid, muw, bbv);
    __syncthreads();

    f16v aq[2], av[2], ak[2];
#pragma unroll
    for (int nt = 0; nt < 2; ++nt)
#pragma unroll
        for (int q = 0; q < 16; ++q) { aq[nt][q] = 0.f; av[nt][q] = 0.f; ak[nt][q] = 0.f; }

    const int r = tid >> 2, kq = tid & 3;
    for (int k0 = 0; k0 < 128; k0 += 32) {
        size_t ga = (size_t)(row0 + r) * 128 + k0 + kq * 8;
        uint4 h4 = *(const uint4*)(p.A0 + ga);
        uint4 l4 = *(const uint4*)(p.A1 + ga);
        if (NORM) {
            u16 h8[8], l8[8], ho[8], lo8[8];
            *(uint4*)h8 = h4; *(uint4*)l8 = l4;
            const int e0 = k0 + kq * 8;
#pragma unroll
            for (int j2 = 0; j2 < 8; ++j2) {
                float v = bf2f(h8[j2]) + bf2f(l8[j2]);
                float x = fmaf(v, muw[e0 + j2], bbv[e0 + j2]);
                u16 hi = bf16r(x);
                ho[j2] = hi; lo8[j2] = bf16r(x - bf2f(hi));
            }
            *(uint4*)&As[0][r][kq * 8] = *(uint4*)ho;
            *(uint4*)&As[1][r][kq * 8] = *(uint4*)lo8;
        } else {
            *(uint4*)&As[0][r][kq * 8] = h4;
            *(uint4*)&As[1][r][kq * 8] = l4;
        }
#pragma unroll
        for (int i = 0; i < 2; ++i) {
            int s = tid + i * 256;
            int rb2 = s >> 2, q = s & 3;
            size_t gb = (size_t)rb2 * 128 + k0 + q * 8;
            *(uint4*)&Bs[0][rb2][q * 8] = *(const uint4*)(p.qh + gb);
            *(uint4*)&Bs[1][rb2][q * 8] = *(const uint4*)(p.ql + gb);
            *(uint4*)&Bs[2][rb2][q * 8] = *(const uint4*)(p.vh + gb);
            *(uint4*)&Bs[3][rb2][q * 8] = *(const uint4*)(p.vl + gb);
            *(uint4*)&Bs[4][rb2][q * 8] = *(const uint4*)(p.kh + gb);
            *(uint4*)&Bs[5][rb2][q * 8] = *(const uint4*)(p.kl + gb);
        }
        __syncthreads();
#pragma unroll
        for (int s = 0; s < 2; ++s) {
            bf8 ah = *(const bf8*)&As[0][wm * 32 + ln][s * 16 + hk * 8];
            bf8 al = *(const bf8*)&As[1][wm * 32 + ln][s * 16 + hk * 8];
#pragma unroll
            for (int nt = 0; nt < 2; ++nt) {
                const int br = wn * 64 + nt * 32 + ln, sc = s * 16 + hk * 8;
                bf8 bqh = *(const bf8*)&Bs[0][br][sc];
                bf8 bql = *(const bf8*)&Bs[1][br][sc];
                bf8 bvh = *(const bf8*)&Bs[2][br][sc];
                bf8 bvl = *(const bf8*)&Bs[3][br][sc];
                bf8 bkh = *(const bf8*)&Bs[4][br][sc];
                bf8 bkl = *(const bf8*)&Bs[5][br][sc];
                aq[nt] = MFMA(ah, bqh, aq[nt]);
                aq[nt] = MFMA(ah, bql, aq[nt]);
                aq[nt] = MFMA(al, bqh, aq[nt]);
                av[nt] = MFMA(ah, bvh, av[nt]);
                av[nt] = MFMA(ah, bvl, av[nt]);
                av[nt] = MFMA(al, bvh, av[nt]);
                ak[nt] = MFMA(ah, bkh, ak[nt]);
                ak[nt] = MFMA(ah, bkl, ak[nt]);
                ak[nt] = MFMA(al, bkh, ak[nt]);
            }
        }
        __syncthreads();
    }

#pragma unroll
    for (int nt = 0; nt < 2; ++nt) {
        int gn = wn * 64 + nt * 32 + ln;
#pragma unroll
        for (int g = 0; g < 4; ++g) {
            int rb = row0 + wm * 32 + g * 8 + hk * 4;
            int bb = rb >> 9, nb = rb & 511;
            u16 pe[4], pv[4];
#pragma unroll
            for (int rr = 0; rr < 4; ++rr) {
                float vq = aq[nt][g * 4 + rr];
                p.sq16[(size_t)(rb + rr) * 128 + gn] =
                    bf16r(1.f / (1.f + __expf(-vq)));
                u16 hv = bf16r(av[nt][g * 4 + rr]);
                u16 he = bf16r(__expf(ak[nt][g * 4 + rr]));
                pe[rr] = he;
                pv[rr] = bf16r(bf2f(hv) * bf2f(he));
            }
            uint2 ue, uv;
            ue.x = pe[0] | ((unsigned)pe[1] << 16);
            ue.y = pe[2] | ((unsigned)pe[3] << 16);
            uv.x = pv[0] | ((unsigned)pv[1] << 16);
            uv.y = pv[2] | ((unsigned)pv[3] << 16);
            *(uint2*)(p.y2t + (size_t)bb * 131072 + (size_t)gn * 512 + nb) = uv;
            *(uint2*)(p.y2t + (size_t)bb * 131072 + (size_t)(128 + gn) * 512 + nb) = ue;
        }
    }
}

// ===========================================================================
// qvk_vk_k: decoder v/k. A = enc = norm2(val2 last layer), applied on load.
// ===========================================================================
struct QV {
    const u16 *A0, *A1;
    const float *ps2, *pw, *pb;
    const u16 *vh, *vl, *kh, *kl;
    u16* y2t;
};

__launch_bounds__(256, 3) __global__ void qvk_vk_k(QV p)
{
    const int tid = threadIdx.x;
    const int lane = tid & 63, wv = tid >> 6;
    const int wm = wv & 1, wn = wv >> 1;
    const int ln = lane & 31, hk = lane >> 5;
    const int row0 = blockIdx.x * 64;

    __shared__ __align__(16) u16 As[2][64][40];
    __shared__ __align__(16) u16 Bs[4][128][40];
    __shared__ float muw[128], bbv[128];

    norm_coef(p.ps2, p.pw, p.pb, blockIdx.x >> 3, tid, muw, bbv);
    __syncthreads();

    f16v av[2], ak[2];
#pragma unroll
    for (int nt = 0; nt < 2; ++nt)
#pragma unroll
        for (int q = 0; q < 16; ++q) { av[nt][q] = 0.f; ak[nt][q] = 0.f; }

    const int r = tid >> 2, kq = tid & 3;
    for (int k0 = 0; k0 < 128; k0 += 32) {
        size_t ga = (size_t)(row0 + r) * 128 + k0 + kq * 8;
        uint4 h4 = *(const uint4*)(p.A0 + ga);
        uint4 l4 = *(const uint4*)(p.A1 + ga);
        {
            u16 h8[8], l8[8], ho[8], lo8[8];
            *(uint4*)h8 = h4; *(uint4*)l8 = l4;
            const int e0 = k0 + kq * 8;
#pragma unroll
            for (int j2 = 0; j2 < 8; ++j2) {
                float v = bf2f(h8[j2]) + bf2f(l8[j2]);
                float x = fmaf(v, muw[e0 + j2], bbv[e0 + j2]);
                u16 hi = bf16r(x);
                ho[j2] = hi; lo8[j2] = bf16r(x - bf2f(hi));
            }
            *(uint4*)&As[0][r][kq * 8] = *(uint4*)ho;
            *(uint4*)&As[1][r][kq * 8] = *(uint4*)lo8;
        }
#pragma unroll
        for (int i = 0; i < 2; ++i) {
            int s = tid + i * 256;
            int rb2 = s >> 2, q = s & 3;
            size_t gb = (size_t)rb2 * 128 + k0 + q * 8;
            *(uint4*)&Bs[0][rb2][q * 8] = *(const uint4*)(p.vh + gb);
            *(uint4*)&Bs[1][rb2][q * 8] = *(const uint4*)(p.vl + gb);
            *(uint4*)&Bs[2][rb2][q * 8] = *(const uint4*)(p.kh + gb);
            *(uint4*)&Bs[3][rb2][q * 8] = *(const uint4*)(p.kl + gb);
        }
        __syncthreads();
#pragma unroll
        for (int s = 0; s < 2; ++s) {
            bf8 ah = *(const bf8*)&As[0][wm * 32 + ln][s * 16 + hk * 8];
            bf8 al = *(const bf8*)&As[1][wm * 32 + ln][s * 16 + hk * 8];
#pragma unroll
            for (int nt = 0; nt < 2; ++nt) {
                const int br = wn * 64 + nt * 32 + ln, sc = s * 16 + hk * 8;
                bf8 bvh = *(const bf8*)&Bs[0][br][sc];
                bf8 bvl = *(const bf8*)&Bs[1][br][sc];
                bf8 bkh = *(const bf8*)&Bs[2][br][sc];
                bf8 bkl = *(const bf8*)&Bs[3][br][sc];
                av[nt] = MFMA(ah, bvh, av[nt]);
                av[nt] = MFMA(ah, bvl, av[nt]);
                av[nt] = MFMA(al, bvh, av[nt]);
                ak[nt] = MFMA(ah, bkh, ak[nt]);
                ak[nt] = MFMA(ah, bkl, ak[nt]);
                ak[nt] = MFMA(al, bkh, ak[nt]);
            }
        }
        __syncthreads();
    }

#pragma unroll
    for (int nt = 0; nt < 2; ++nt) {
        int gn = wn * 64 + nt * 32 + ln;
#pragma unroll
        for (int g = 0; g < 4; ++g) {
            int rb = row0 + wm * 32 + g * 8 + hk * 4;
            int bb = rb >> 9, nb = rb & 511;
            u16 pe[4], pv[4];
#pragma unroll
            for (int rr = 0; rr < 4; ++rr) {
                u16 hv = bf16r(av[nt][g * 4 + rr]);
                u16 he = bf16r(__expf(ak[nt][g * 4 + rr]));
                pe[rr] = he;
                pv[rr] = bf16r(bf2f(hv) * bf2f(he));
            }
            uint2 ue, uv;
            ue.x = pe[0] | ((unsigned)pe[1] << 16);
            ue.y = pe[2] | ((unsigned)pe[3] << 16);
            uv.x = pv[0] | ((unsigned)pv[1] << 16);
            uv.y = pv[2] | ((unsigned)pv[3] << 16);
            *(uint2*)(p.y2t + (size_t)bb * 131072 + (size_t)gn * 512 + nb) = uv;
            *(uint2*)(p.y2t + (size_t)bb * 131072 + (size_t)(128 + gn) * 512 + nb) = ue;
        }
    }
}

// ===========================================================================
// aft2_k: AFT aggregation, num+den in one block.
// OPA1: A = exp(ascale*a16); OPA3: A = exp(a16) (prefused decoder plane).
// SG1: multiply staged sigmoid plane; SG2: sigmoid(gq1 + cap*dWq) inline.
// RES1: out = x + pv (x from X planes, NORM-applied if NORM), writes val1
//       hi/lo + per-(b,e) partial stats to ps1. RES0: out = pv (decoder).
// ===========================================================================
struct AP2 {
    const u16 *A16;
    const u16 *B0, *sq;
    const u16 *X0, *X1;
    const float *ps2, *pw, *pb;
    u16 *gh, *gl;
    float *ps1;
    const float *s1, *s2; int s2i;
    const float *gq1, *cap, *dWq;
};

template <int OPA, int SG, int RES, int NORM>
__launch_bounds__(256, 3) __global__ void aft2_k(AP2 p)
{
    const int tid = threadIdx.x;
    const int lane = tid & 63, wv = tid >> 6;
    const int wm = wv & 1, wn = wv >> 1;
    const int ln = lane & 31, hk = lane >> 5;

    const int id = blockIdx.x;
    const int xcd = id & 7, slot = id >> 3;
    const int bz = xcd * 8 + (slot >> 3);
    const int row0 = (slot & 7) * 64;

    __shared__ __align__(16) u16 As[2][64][40];
    __shared__ __align__(16) u16 Bs[2][256][40];

    f16v acc[4];
#pragma unroll
    for (int j = 0; j < 4; ++j)
#pragma unroll
        for (int q = 0; q < 16; ++q) acc[j][q] = 0.f;

    const float ascale = (OPA == 1) ? p.s1[0] * p.s2[p.s2i] : 0.f;
    const u16* Af = p.A16 + (size_t)bz * 262144 + (size_t)row0 * 512;
    const u16* Bb = p.B0 + (size_t)bz * 131072;

    const int r = tid >> 2, kq = tid & 3;
    uint4 va;
    uint4 vb[4];

#define AFT_LOAD(K0)                                                          \
    {                                                                         \
        va = *(const uint4*)(Af + (size_t)r * 512 + (K0) + kq * 8);           \
        size_t gb = (size_t)tid * 512 + (K0);                                 \
        _Pragma("unroll") for (int q = 0; q < 4; ++q)                         \
            vb[q] = *(const uint4*)(Bb + gb + q * 8);                         \
    }

#define AFT_WRITE(BUF)                                                        \
    {                                                                         \
        u16 a8[8];                                                            \
        *(uint4*)a8 = va;                                                     \
        float f[8];                                                           \
        _Pragma("unroll") for (int j = 0; j < 8; ++j) {                       \
            float t = bf2f(a8[j]);                                            \
            if (OPA == 1) t *= ascale;                                        \
            f[j] = __expf(t);                                                 \
        }                                                                     \
        uint4 pk;                                                             \
        pk.x = bf16r(f[0]) | ((unsigned)bf16r(f[1]) << 16);                   \
        pk.y = bf16r(f[2]) | ((unsigned)bf16r(f[3]) << 16);                   \
        pk.z = bf16r(f[4]) | ((unsigned)bf16r(f[5]) << 16);                   \
        pk.w = bf16r(f[6]) | ((unsigned)bf16r(f[7]) << 16);                   \
        *(uint4*)&As[BUF][r][kq * 8] = pk;                                    \
        _Pragma("unroll") for (int q = 0; q < 4; ++q)                         \
            *(uint4*)&Bs[BUF][tid][q * 8] = vb[q];                            \
    }

#define AFT_COMPUTE(BUF)                                                      \
    {                                                                         \
        _Pragma("unroll") for (int s = 0; s < 2; ++s) {                       \
            bf8 ah = *(const bf8*)&As[BUF][wm * 32 + ln][s * 16 + hk * 8];    \
            _Pragma("unroll") for (int j = 0; j < 4; ++j) {                   \
                int br = ((j >> 1) << 7) + wn * 64 + ((j & 1) << 5) + ln;     \
                bf8 bh = *(const bf8*)&Bs[BUF][br][s * 16 + hk * 8];          \
                acc[j] = MFMA(ah, bh, acc[j]);                                \
            }                                                                 \
        }                                                                     \
    }

    AFT_LOAD(0);
    AFT_WRITE(0);
    __syncthreads();

    int cur = 0;
    for (int k0 = 32; k0 < 512; k0 += 32) {
        AFT_LOAD(k0);
        AFT_COMPUTE(cur);
        AFT_WRITE(cur ^ 1);
        __syncthreads();
        cur ^= 1;
    }
    AFT_COMPUTE(cur);

#undef AFT_LOAD
#undef AFT_WRITE
#undef AFT_COMPUTE

    __syncthreads();                 // As/Bs dead; reuse As as float scratch
    float* fl = (float*)&As[0][0][0];
    float* muw = fl;                 // [128]
    float* bbv = fl + 128;           // [128]
    float* red = fl + 256;           // [4][128][2]
    if (RES && NORM) norm_coef(p.ps2, p.pw, p.pb, bz, tid, muw, bbv);
    __syncthreads();

    const int rslot = wm * 2 + hk;
    const u16* sqb = (SG == 1) ? (p.sq + (size_t)bz * 65536) : (const u16*)0;
    u16* ghb = p.gh + (size_t)bz * 65536;
    u16* glb = p.gl + (size_t)bz * 65536;
#pragma unroll
    for (int j = 0; j < 2; ++j) {
        int e = wn * 64 + j * 32 + ln;
        float ssum = 0.f, sq2 = 0.f;
#pragma unroll
        for (int g = 0; g < 4; ++g) {
#pragma unroll
            for (int rr = 0; rr < 4; ++rr) {
                int row = row0 + wm * 32 + g * 8 + hk * 4 + rr;
                float num = acc[j][g * 4 + rr];
                float den = acc[j + 2][g * 4 + rr];
                float pv = num / den;
                if (SG == 1) pv *= bf2f(sqb[(size_t)row * 128 + e]);
                if (SG == 2) {
                    float qv = fmaf(p.cap[(size_t)bz * 512 + row],
                                    p.dWq[128 * 128 + e], p.gq1[e]);
                    pv *= 1.f / (1.f + __expf(-qv));
                }
                float outv = pv;
                if (RES) {
                    size_t xa = (size_t)bz * 65536 + (size_t)row * 128 + e;
                    float xv = bf2f(p.X0[xa]) + bf2f(p.X1[xa]);
                    if (NORM) xv = fmaf(xv, muw[e], bbv[e]);
                    outv = xv + pv;
                }
                u16 hi = bf16r(outv);
                u16 lo = bf16r(outv - bf2f(hi));
                ghb[(size_t)row * 128 + e] = hi;
                glb[(size_t)row * 128 + e] = lo;
                if (RES) {
                    float vr = bf2f(hi) + bf2f(lo);
                    ssum += vr;
                    sq2 = fmaf(vr, vr, sq2);
                }
            }
        }
        if (RES) {
            red[rslot * 256 + e * 2] = ssum;
            red[rslot * 256 + e * 2 + 1] = sq2;
        }
    }
    if (RES) {
        __syncthreads();
        if (tid < 128) {
            float s = red[tid * 2] + red[256 + tid * 2] +
                      red[512 + tid * 2] + red[768 + tid * 2];
            float q = red[tid * 2 + 1] + red[256 + tid * 2 + 1] +
                      red[512 + tid * 2 + 1] + red[768 + tid * 2 + 1];
            size_t po = ((size_t)bz * 8 + (row0 >> 6)) * 256 + tid * 2;
            p.ps1[po] = s;
            p.ps1[po + 1] = q;
        }
    }
}

// ===========================================================================
// ffn12_k: fused norm1-apply + FFN + residual + stats2.
// A-load: h = (val1-mu)*rs*w+b from vh1/vl1 + pstats1.
// Epilogue: re-reads val1 (L2-hot), val2 = h + ff2, writes val2 hi/lo +
// pstats2 partials. ff2 never touches HBM.
// ===========================================================================
struct F12 {
    const u16 *V0, *V1;
    const float *ps1, *n1w, *n1b;
    const u16 *w1h, *w1l;      // [512][128]
    const u16 *w2h, *w2l;      // [128][512]
    const float *b1, *b2;
    u16 *o0, *o1;
    float *ps2;
};

__launch_bounds__(512, 2) __global__ void ffn12_k(F12 p)
{
    const int tid = threadIdx.x;
    const int lane = tid & 63, wv = tid >> 6;
    const int wm = wv & 1, wn = wv >> 1;
    const int ln = lane & 31, hk = lane >> 5;
    const int row0 = blockIdx.x * 64;
    const int b = blockIdx.x >> 3;

    __shared__ __align__(16) u16 Ws[2][2][128][72];
    __shared__ __align__(16) u16 ff1c[4][64][136];
    __shared__ float muw1[128], bb1[128];

    norm_coef(p.ps1, p.n1w, p.n1b, b, tid, muw1, bb1);
    __syncthreads();

    bf8 ar0[8], ar1[8];
    {
        const size_t arow = (size_t)(row0 + wm * 32 + ln) * 128;
#pragma unroll
        for (int s = 0; s < 8; ++s) {
            uint4 h4 = *(const uint4*)(p.V0 + arow + s * 16 + hk * 8);
            uint4 l4 = *(const uint4*)(p.V1 + arow + s * 16 + hk * 8);
            u16 h8[8], l8[8], ho[8], lo8[8];
            *(uint4*)h8 = h4; *(uint4*)l8 = l4;
            const int e0 = s * 16 + hk * 8;
#pragma unroll
            for (int j2 = 0; j2 < 8; ++j2) {
                float v = bf2f(h8[j2]) + bf2f(l8[j2]);
                float h = fmaf(v, muw1[e0 + j2], bb1[e0 + j2]);
                u16 hi = bf16r(h);
                ho[j2] = hi; lo8[j2] = bf16r(h - bf2f(hi));
            }
            ar0[s] = *(bf8*)ho;
            ar1[s] = *(bf8*)lo8;
        }
    }

    const int lcol = wn * 32 + ln;
    const int sc_ = tid >> 3, sq_ = tid & 7;
    uint4 wr[2][2];

#define F_LOAD1(CT, KC)                                                       \
    {                                                                         \
        _Pragma("unroll") for (int pl = 0; pl < 2; ++pl) {                    \
            const u16* src = pl ? p.w1l : p.w1h;                              \
            _Pragma("unroll") for (int it = 0; it < 2; ++it) {                \
                int c = sc_ + it * 64;                                        \
                wr[pl][it] = *(const uint4*)(src +                            \
                    (size_t)((CT) * 128 + c) * 128 + (KC) * 64 + sq_ * 8);    \
            }                                                                 \
        }                                                                     \
    }

#define F_LOAD2(J)                                                            \
    {                                                                         \
        _Pragma("unroll") for (int pl = 0; pl < 2; ++pl) {                    \
            const u16* src = pl ? p.w2l : p.w2h;                              \
            _Pragma("unroll") for (int it = 0; it < 2; ++it) {                \
                int c = sc_ + it * 64;                                        \
                wr[pl][it] = *(const uint4*)(src +                            \
                    (size_t)c * 512 + (J) * 64 + sq_ * 8);                    \
            }                                                                 \
        }                                                                     \
    }

#define F_STORE(BUF)                                                          \
    {                                                                         \
        _Pragma("unroll") for (int pl = 0; pl < 2; ++pl)                      \
            _Pragma("unroll") for (int it = 0; it < 2; ++it)                  \
                *(uint4*)&Ws[BUF][pl][sc_ + it * 64][sq_ * 8] = wr[pl][it];   \
    }

    // ---- phase 1 ----
    F_LOAD1(0, 0);
    F_STORE(0);
    __syncthreads();
    int buf = 0;
    f16v a0, a1, a2;
#pragma unroll
    for (int st = 0; st < 8; ++st) {
        const int ct = st >> 1, kc = st & 1;
        if (st < 7) { F_LOAD1((st + 1) >> 1, (st + 1) & 1); }
        else        { F_LOAD2(0); }
        if (kc == 0) {
#pragma unroll
            for (int q = 0; q < 16; ++q) { a0[q] = 0.f; a1[q] = 0.f; a2[q] = 0.f; }
        }
#pragma unroll
        for (int s = 0; s < 4; ++s) {
            bf8 bh = *(const bf8*)&Ws[buf][0][lcol][s * 16 + hk * 8];
            bf8 bl = *(const bf8*)&Ws[buf][1][lcol][s * 16 + hk * 8];
            a0 = MFMA(ar0[kc * 4 + s], bh, a0);
            a1 = MFMA(ar0[kc * 4 + s], bl, a1);
            a2 = MFMA(ar1[kc * 4 + s], bh, a2);
        }
        if (kc == 1) {
            float bv = p.b1[ct * 128 + lcol];
#pragma unroll
            for (int g = 0; g < 4; ++g)
#pragma unroll
                for (int rr = 0; rr < 4; ++rr) {
                    int lr = wm * 32 + g * 8 + hk * 4 + rr;
                    float v = a0[g * 4 + rr] + a1[g * 4 + rr] + a2[g * 4 + rr] + bv;
                    ff1c[ct][lr][lcol] = bf16r(fmaxf(v, 0.f));
                }
        }
        F_STORE(buf ^ 1);
        __syncthreads();
        buf ^= 1;
    }

    // ---- phase 2 ----
    f16v c0, c1;
#pragma unroll
    for (int q = 0; q < 16; ++q) { c0[q] = 0.f; c1[q] = 0.f; }
#pragma unroll
    for (int j = 0; j < 8; ++j) {
        if (j < 7) F_LOAD2(j + 1);
#pragma unroll
        for (int s = 0; s < 4; ++s) {
            bf8 af = *(const bf8*)&ff1c[j >> 1][wm * 32 + ln]
                                      [(j & 1) * 64 + s * 16 + hk * 8];
            bf8 bh = *(const bf8*)&Ws[buf][0][lcol][s * 16 + hk * 8];
            bf8 bl = *(const bf8*)&Ws[buf][1][lcol][s * 16 + hk * 8];
            c0 = MFMA(af, bh, c0);
            c1 = MFMA(af, bl, c1);
        }
        if (j < 7) {
            F_STORE(buf ^ 1);
            __syncthreads();
            buf ^= 1;
        }
    }

#undef F_LOAD1
#undef F_LOAD2
#undef F_STORE

    // ---- epilogue: val2 = h + ff2, write + stats2 ----
    const float bv = p.b2[lcol];
    const float mwl = muw1[lcol], bbl = bb1[lcol];
    float ssum = 0.f, sq2 = 0.f;
#pragma unroll
    for (int g = 0; g < 4; ++g)
#pragma unroll
        for (int rr = 0; rr < 4; ++rr) {
            int rb = row0 + wm * 32 + g * 8 + hk * 4 + rr;
            size_t xa = (size_t)rb * 128 + lcol;
            float v1 = bf2f(p.V0[xa]) + bf2f(p.V1[xa]);
            float h = fmaf(v1, mwl, bbl);
            float val2 = h + c0[g * 4 + rr] + c1[g * 4 + rr] + bv;
            u16 hi = bf16r(val2);
            u16 lo = bf16r(val2 - bf2f(hi));
            p.o0[xa] = hi;
            p.o1[xa] = lo;
            float vr = bf2f(hi) + bf2f(lo);
            ssum += vr;
            sq2 = fmaf(vr, vr, sq2);
        }
    __syncthreads();                 // ff1c dead; reuse as reduction scratch
    float* red = (float*)&ff1c[0][0][0];
    red[(wm * 2 + hk) * 256 + lcol * 2] = ssum;
    red[(wm * 2 + hk) * 256 + lcol * 2 + 1] = sq2;
    __syncthreads();
    if (tid < 128) {
        float s = red[tid * 2] + red[256 + tid * 2] +
                  red[512 + tid * 2] + red[768 + tid * 2];
        float q = red[tid * 2 + 1] + red[256 + tid * 2 + 1] +
                  red[512 + tid * 2 + 1] + red[768 + tid * 2 + 1];
        size_t po = ((size_t)b * 8 + (blockIdx.x & 7)) * 256 + tid * 2;
        p.ps2[po] = s;
        p.ps2[po + 1] = q;
    }
}

// ===========================================================================
// score_sm_k: fused score+softmax, 1024 threads (16 waves, 2x8), 64 rows x
// 512 cols per block. B = enc, normalized on load from (val2, pstats2).
// ===========================================================================
struct SP2 {
    const u16 *A0, *A1, *B0, *B1;
    const float *ps2, *pw, *pb;
    float* out;
    const float *cd, *cm;
    const float *s1, *s2;
};

__launch_bounds__(1024, 4) __global__ void score_sm_k(SP2 p)
{
    const int tid = threadIdx.x;
    const int lane = tid & 63, wv = tid >> 6;
    const int wm = wv & 1, wn = wv >> 1;
    const int ln = lane & 31, hk = lane >> 5;

    const int id = blockIdx.x;
    const int xcd = id & 7, s_ = id >> 3;
    const int bz = xcd * 8 + (s_ & 7);
    const int row0 = (s_ >> 3) * 64;

    __shared__ __align__(16) u16 As[2][64][136];
    __shared__ __align__(16) u16 Bs[2][512][40];
    __shared__ float rs[8][64];
    __shared__ float muw2[128], bb2[128];

    norm_coef(p.ps2, p.pw, p.pb, bz, tid, muw2, bb2);

    // stage A (aft rows) once: 2 planes x 64 rows x 128 cols
#pragma unroll
    for (int i = 0; i < 2; ++i) {
        int idx = tid + i * 1024;
        int pl = idx >> 10, rem = idx & 1023;
        int row = rem >> 4, q = rem & 15;
        const u16* src = pl ? p.A1 : p.A0;
        *(uint4*)&As[pl][row][q * 8] =
            *(const uint4*)(src + ((size_t)bz * 512 + row0 + row) * 128 + q * 8);
    }
    __syncthreads();

    const float sp = p.s1[0] * p.s2[0];

    f16v accs[2];
#pragma unroll
    for (int nt = 0; nt < 2; ++nt)
#pragma unroll
        for (int q = 0; q < 16; ++q) accs[nt][q] = 0.f;

    for (int k0 = 0; k0 < 128; k0 += 32) {
#pragma unroll
        for (int i = 0; i < 2; ++i) {
            int idx = tid + i * 1024;
            int row = idx >> 2, q = idx & 3;
            size_t ga = ((size_t)bz * 512 + row) * 128 + k0 + q * 8;
            uint4 h4 = *(const uint4*)(p.B0 + ga);
            uint4 l4 = *(const uint4*)(p.B1 + ga);
            u16 h8[8], l8[8], ho[8], lo8[8];
            *(uint4*)h8 = h4; *(uint4*)l8 = l4;
            const int e0 = k0 + q * 8;
#pragma unroll
            for (int j2 = 0; j2 < 8; ++j2) {
                float v = bf2f(h8[j2]) + bf2f(l8[j2]);
                float x = fmaf(v, muw2[e0 + j2], bb2[e0 + j2]);
                u16 hi = bf16r(x);
                ho[j2] = hi; lo8[j2] = bf16r(x - bf2f(hi));
            }
            *(uint4*)&Bs[0][row][q * 8] = *(uint4*)ho;
            *(uint4*)&Bs[1][row][q * 8] = *(uint4*)lo8;
        }
        __syncthreads();
#pragma unroll
        for (int s = 0; s < 2; ++s) {
            bf8 ah = *(const bf8*)&As[0][wm * 32 + ln][k0 + s * 16 + hk * 8];
            bf8 al = *(const bf8*)&As[1][wm * 32 + ln][k0 + s * 16 + hk * 8];
#pragma unroll
            for (int nt = 0; nt < 2; ++nt) {
                bf8 bh = *(const bf8*)&Bs[0][wn * 64 + nt * 32 + ln][s * 16 + hk * 8];
                bf8 bl = *(const bf8*)&Bs[1][wn * 64 + nt * 32 + ln][s * 16 + hk * 8];
                accs[nt] = MFMA(ah, bh, accs[nt]);
                accs[nt] = MFMA(ah, bl, accs[nt]);
                accs[nt] = MFMA(al, bh, accs[nt]);
            }
        }
        __syncthreads();
    }

    // epilogue: score -> exp (kept in accs); cd/cm loaded inline per nt
    float rsum[16];
#pragma unroll
    for (int nt = 0; nt < 2; ++nt) {
        const int gn = wn * 64 + nt * 32 + ln;
        float cdv[16], cmv[16];
#pragma unroll
        for (int g = 0; g < 4; ++g)
#pragma unroll
            for (int rr = 0; rr < 4; ++rr) {
                int grow = row0 + wm * 32 + g * 8 + hk * 4 + rr;
                size_t ix = (size_t)bz * 262144 + (size_t)grow * 512 + gn;
                cdv[g * 4 + rr] = p.cd[ix];
                cmv[g * 4 + rr] = p.cm[ix];
            }
#pragma unroll
        for (int i = 0; i < 16; ++i) {
            float sc = fmaf(accs[nt][i], SQRT_E_INV, sp * cdv[i]);
            float e2 = __expf(2.f * sc);
            float th = 1.f - 2.f / (e2 + 1.f);
            float ev = __expf(10.f * th + cmv[i]);
            accs[nt][i] = ev;
            if (nt == 0) rsum[i] = ev; else rsum[i] += ev;
        }
    }

#pragma unroll
    for (int i = 0; i < 16; ++i) {
#pragma unroll
        for (int o = 1; o < 32; o <<= 1) rsum[i] += __shfl_xor(rsum[i], o);
    }
    __syncthreads();
    if (ln == 0) {
#pragma unroll
        for (int i = 0; i < 16; ++i) {
            int lr = wm * 32 + (i >> 2) * 8 + hk * 4 + (i & 3);
            rs[wn][lr] = rsum[i];
        }
    }
    __syncthreads();
    float invr[16];
#pragma unroll
    for (int i = 0; i < 16; ++i) {
        int lr = wm * 32 + (i >> 2) * 8 + hk * 4 + (i & 3);
        float t = rs[0][lr] + rs[1][lr] + rs[2][lr] + rs[3][lr]
                + rs[4][lr] + rs[5][lr] + rs[6][lr] + rs[7][lr];
        invr[i] = 1.f / t;
    }

#pragma unroll
    for (int nt = 0; nt < 2; ++nt) {
        int gn = wn * 64 + nt * 32 + ln;
#pragma unroll
        for (int g = 0; g < 4; ++g)
#pragma unroll
            for (int rr = 0; rr < 4; ++rr) {
                int grow = row0 + wm * 32 + g * 8 + hk * 4 + rr;
                size_t ix = (size_t)bz * 262144 + (size_t)grow * 512 + gn;
                p.out[ix] = accs[nt][g * 4 + rr] * invr[g * 4 + rr];
            }
    }
}

// ===========================================================================
__global__ void wprep_k(const float* __restrict__ W, u16* __restrict__ Th,
                        u16* __restrict__ Tl, int K, int N)
{
    const int z = blockIdx.z;
    const float* Wz = W + (size_t)z * K * N;
    u16* Hh = Th + (size_t)z * K * N;
    u16* Hl = Tl + (size_t)z * K * N;
    __shared__ float t[32][33];
    const int j = threadIdx.x & 31, i0 = threadIdx.x >> 5;
    const int k0 = blockIdx.x * 32, n0 = blockIdx.y * 32;
    for (int i = i0; i < 32; i += 8)
        t[i][j] = Wz[(size_t)(k0 + i) * N + n0 + j];
    __syncthreads();
    for (int i = i0; i < 32; i += 8) {
        float v = t[j][i];
        u16 h = bf16r(v);
        u16 l = bf16r(v - bf2f(h));
        size_t o = (size_t)(n0 + i) * K + k0 + j;
        Hh[o] = h; Hl[o] = l;
    }
}

__global__ void distprep_k(const float* __restrict__ src, u16* __restrict__ dst)
{
    size_t i = ((size_t)blockIdx.x * 256 + threadIdx.x) * 8;
    float4 f0 = *(const float4*)(src + i);
    float4 f1 = *(const float4*)(src + i + 4);
    uint4 pk;
    pk.x = bf16r(f0.x) | ((unsigned)bf16r(f0.y) << 16);
    pk.y = bf16r(f0.z) | ((unsigned)bf16r(f0.w) << 16);
    pk.z = bf16r(f1.x) | ((unsigned)bf16r(f1.y) << 16);
    pk.w = bf16r(f1.z) | ((unsigned)bf16r(f1.w) << 16);
    *(uint4*)(dst + i) = pk;
}

__global__ void decprep_k(const float* __restrict__ cd, const float* __restrict__ nf,
                          const float* __restrict__ s1, const float* __restrict__ s2,
                          u16* __restrict__ dst)
{
    const float da = s1[0] * s2[0];
    size_t i = ((size_t)blockIdx.x * 256 + threadIdx.x) * 8;
    float4 c0 = *(const float4*)(cd + i);
    float4 c1 = *(const float4*)(cd + i + 4);
    float4 m0 = *(const float4*)(nf + i);
    float4 m1 = *(const float4*)(nf + i + 4);
    uint4 pk;
    pk.x = bf16r(fmaf(da, c0.x, m0.x)) | ((unsigned)bf16r(fmaf(da, c0.y, m0.y)) << 16);
    pk.y = bf16r(fmaf(da, c0.z, m0.z)) | ((unsigned)bf16r(fmaf(da, c0.w, m0.w)) << 16);
    pk.z = bf16r(fmaf(da, c1.x, m1.x)) | ((unsigned)bf16r(fmaf(da, c1.y, m1.y)) << 16);
    pk.w = bf16r(fmaf(da, c1.z, m1.z)) | ((unsigned)bf16r(fmaf(da, c1.w, m1.w)) << 16);
    *(uint4*)(dst + i) = pk;
}

__global__ void embed_k(const float* __restrict__ data, const float* __restrict__ W,
                        const float* __restrict__ bias,
                        u16* __restrict__ xh, u16* __restrict__ xl)
{
    size_t idx = (size_t)blockIdx.x * 256 + threadIdx.x;
    int e = idx & 127;
    size_t bn = idx >> 7;
    float v = fmaf(data[bn * 2], W[e], fmaf(data[bn * 2 + 1], W[128 + e], bias[e]));
    u16 h = bf16r(v);
    xh[idx] = h;
    xl[idx] = bf16r(v - bf2f(h));
}

// gq1[o] = n2b_last @ dWq[0:128] — instance norm makes the node-mean of enc
// exactly n2_b, so the decoder global-mean query is batch-independent.
__global__ void gqprep_k(const float* __restrict__ n2b,
                         const float* __restrict__ dWq, float* __restrict__ gq1)
{
    int o = threadIdx.x;
    float acc = 0.f;
    for (int e = 0; e < 128; ++e) acc = fmaf(n2b[e], dWq[e * 128 + o], acc);
    gq1[o] = acc;
}

// ===========================================================================
extern "C" void kernel_launch(void* const* d_in, const int* in_sizes, int n_in,
                              void* d_out, int out_size, void* d_ws, size_t ws_size,
                              hipStream_t stream)
{
    const float* data      = (const float*)d_in[0];
    const float* dist      = (const float*)d_in[1];
    const float* cur_dist  = (const float*)d_in[2];
    const float* capacity  = (const float*)d_in[3];
    const float* ninf      = (const float*)d_in[4];
    const float* log_scale = (const float*)d_in[5];
    const float* emb_W     = (const float*)d_in[6];
    const float* emb_b     = (const float*)d_in[7];
    const float* Wq        = (const float*)d_in[8];
    const float* Wk        = (const float*)d_in[9];
    const float* Wv        = (const float*)d_in[10];
    const float* aft_alpha = (const float*)d_in[11];
    const float* n1_w      = (const float*)d_in[12];
    const float* n1_b      = (const float*)d_in[13];
    const float* ffW1      = (const float*)d_in[14];
    const float* ffb1      = (const float*)d_in[15];
    const float* ffW2      = (const float*)d_in[16];
    const float* ffb2      = (const float*)d_in[17];
    const float* n2_w      = (const float*)d_in[18];
    const float* n2_b      = (const float*)d_in[19];
    const float* dWq       = (const float*)d_in[20];
    const float* dWk       = (const float*)d_in[21];
    const float* dWv       = (const float*)d_in[22];
    const float* dec_alpha = (const float*)d_in[23];
    const float* p_alpha   = (const float*)d_in[24];
    float* out = (float*)d_out;

    char* W = (char*)d_ws;
    size_t off = 0;
    auto take = [&](size_t n) { void* pp = W + off; off += (n + 255) & ~(size_t)255; return pp; };
    const size_t SZP = (size_t)B_ * N_ * E_ * 2;   // 8 MB bf16 plane

    u16* xh   = (u16*)take(SZP);
    u16* xl   = (u16*)take(SZP);
    u16* hh   = (u16*)take(SZP);
    u16* hl   = (u16*)take(SZP);
    u16* sq16 = (u16*)take(SZP);
    u16* vh1  = (u16*)take(SZP);
    u16* vl1  = (u16*)take(SZP);
    u16* vh2  = (u16*)take(SZP);
    u16* vl2  = (u16*)take(SZP);
    u16* y2t  = (u16*)take(2 * SZP);
    u16* d16  = (u16*)take((size_t)B_ * N_ * N_ * 2);      // 32 MB bf16 dist
    float* ps1 = (float*)take(64 * 8 * 128 * 2 * 4);       // 512 KB
    float* ps2 = (float*)take(64 * 8 * 128 * 2 * 4);
    u16* wqt_h = (u16*)take(196608); u16* wqt_l = (u16*)take(196608);
    u16* wkt_h = (u16*)take(196608); u16* wkt_l = (u16*)take(196608);
    u16* wvt_h = (u16*)take(196608); u16* wvt_l = (u16*)take(196608);
    u16* w1t_h = (u16*)take(786432); u16* w1t_l = (u16*)take(786432);
    u16* w2t_h = (u16*)take(786432); u16* w2t_l = (u16*)take(786432);
    u16* dkt_h = (u16*)take(32768);  u16* dkt_l = (u16*)take(32768);
    u16* dvt_h = (u16*)take(32768);  u16* dvt_l = (u16*)take(32768);
    float* gq1 = (float*)take(512);
    if (ws_size < off) return;

    u16* am16 = d16;   // decoder A-plane aliases d16 (dead after encoder)

    // ---- weight prep ----
    wprep_k<<<dim3(4, 4, 6), 256, 0, stream>>>(Wq, wqt_h, wqt_l, 128, 128);
    wprep_k<<<dim3(4, 4, 6), 256, 0, stream>>>(Wk, wkt_h, wkt_l, 128, 128);
    wprep_k<<<dim3(4, 4, 6), 256, 0, stream>>>(Wv, wvt_h, wvt_l, 128, 128);
    wprep_k<<<dim3(4, 16, 6), 256, 0, stream>>>(ffW1, w1t_h, w1t_l, 128, 512);
    wprep_k<<<dim3(16, 4, 6), 256, 0, stream>>>(ffW2, w2t_h, w2t_l, 512, 128);
    wprep_k<<<dim3(4, 4, 1), 256, 0, stream>>>(dWk, dkt_h, dkt_l, 128, 128);
    wprep_k<<<dim3(4, 4, 1), 256, 0, stream>>>(dWv, dvt_h, dvt_l, 128, 128);

    distprep_k<<<8192, 256, 0, stream>>>(dist, d16);
    embed_k<<<16384, 256, 0, stream>>>(data, emb_W, emb_b, xh, xl);

    for (int l = 0; l < L_; ++l) {
        const u16* cxh = l ? vh2 : xh;
        const u16* cxl = l ? vl2 : xl;
        const float* ppw = l ? (n2_w + (l - 1) * 128) : n2_w;
        const float* ppb = l ? (n2_b + (l - 1) * 128) : n2_b;

        Q3 q3{};
        q3.A0 = cxh; q3.A1 = cxl;
        q3.ps2 = ps2; q3.pw = ppw; q3.pb = ppb;
        q3.qh = wqt_h + l * 16384; q3.ql = wqt_l + l * 16384;
        q3.vh = wvt_h + l * 16384; q3.vl = wvt_l + l * 16384;
        q3.kh = wkt_h + l * 16384; q3.kl = wkt_l + l * 16384;
        q3.sq16 = sq16; q3.y2t = y2t;
        if (l == 0) qvk3_k<0><<<512, 256, 0, stream>>>(q3);
        else        qvk3_k<1><<<512, 256, 0, stream>>>(q3);

        AP2 ap{};
        ap.A16 = d16; ap.B0 = y2t; ap.sq = sq16;
        ap.X0 = cxh; ap.X1 = cxl;
        ap.ps2 = ps2; ap.pw = ppw; ap.pb = ppb;
        ap.gh = vh1; ap.gl = vl1; ap.ps1 = ps1;
        ap.s1 = log_scale; ap.s2 = aft_alpha; ap.s2i = l;
        if (l == 0) aft2_k<1, 1, 1, 0><<<512, 256, 0, stream>>>(ap);
        else        aft2_k<1, 1, 1, 1><<<512, 256, 0, stream>>>(ap);

        F12 f12{};
        f12.V0 = vh1; f12.V1 = vl1;
        f12.ps1 = ps1; f12.n1w = n1_w + l * 128; f12.n1b = n1_b + l * 128;
        f12.w1h = w1t_h + l * 65536; f12.w1l = w1t_l + l * 65536;
        f12.w2h = w2t_h + l * 65536; f12.w2l = w2t_l + l * 65536;
        f12.b1 = ffb1 + l * 512; f12.b2 = ffb2 + l * 128;
        f12.o0 = vh2; f12.o1 = vl2; f12.ps2 = ps2;
        ffn12_k<<<512, 512, 0, stream>>>(f12);
    }

    // ---- decoder ---- (enc = norm2(vh2/vl2, ps2, n2[L-1]))
    {
        const float* lw = n2_w + (L_ - 1) * 128;
        const float* lb = n2_b + (L_ - 1) * 128;

        QV qv{};
        qv.A0 = vh2; qv.A1 = vl2;
        qv.ps2 = ps2; qv.pw = lw; qv.pb = lb;
        qv.vh = dvt_h; qv.vl = dvt_l;
        qv.kh = dkt_h; qv.kl = dkt_l;
        qv.y2t = y2t;
        qvk_vk_k<<<512, 256, 0, stream>>>(qv);

        gqprep_k<<<1, 128, 0, stream>>>(lb, dWq, gq1);
        decprep_k<<<8192, 256, 0, stream>>>(cur_dist, ninf, log_scale, dec_alpha, am16);

        AP2 ap{};
        ap.A16 = am16; ap.B0 = y2t;
        ap.gh = hh; ap.gl = hl;
        ap.s1 = log_scale; ap.s2 = dec_alpha; ap.s2i = 0;
        ap.gq1 = gq1; ap.cap = capacity; ap.dWq = dWq;
        aft2_k<3, 2, 0, 0><<<512, 256, 0, stream>>>(ap);

        SP2 sp{};
        sp.A0 = hh; sp.A1 = hl; sp.B0 = vh2; sp.B1 = vl2;
        sp.ps2 = ps2; sp.pw = lw; sp.pb = lb;
        sp.out = out; sp.cd = cur_dist; sp.cm = ninf;
        sp.s1 = log_scale; sp.s2 = p_alpha;
        score_sm_k<<<512, 1024, 0, stream>>>(sp);
    }
}